// Round 1
// baseline (490.578 us; speedup 1.0000x reference)
//
#include <hip/hip_runtime.h>
#include <math.h>

// ---------------- problem constants ----------------
#define B_    64
#define S_    512
#define HID_  256
#define NH_   4
#define DH_   64
#define BH_   (B_*NH_)            // 256 head-batches
#define BS_   (B_*S_)             // 32768 rows
#define TSZ   (BH_*S_*DH_)        // 8,388,608 bf16 elems per projected tensor
#define PSN   (BH_*S_)            // 131072 rows (per-head row-norm arrays)
#define MEANH_ELEMS (BS_*HID_)    // 8,388,608
#define PROBS_OFF   (2*MEANH_ELEMS)

typedef __attribute__((ext_vector_type(8))) short s16x8;
typedef __attribute__((ext_vector_type(4))) short s16x4;
typedef __attribute__((ext_vector_type(4))) float f32x4;

#define MFMA16(acc, a, b) (acc) = __builtin_amdgcn_mfma_f32_16x16x32_bf16((a), (b), (acc), 0, 0, 0)

static __device__ __forceinline__ short f2bf(float f) {
    union { float f; unsigned u; } a; a.f = f;
    unsigned r = a.u + 0x7fffu + ((a.u >> 16) & 1u);   // RNE
    return (short)(r >> 16);
}
static __device__ __forceinline__ float b2f(short s) {
    union { unsigned u; float f; } a; a.u = ((unsigned)(unsigned short)s) << 16;
    return a.f;
}
static __device__ __forceinline__ unsigned cvt_pk_bf16(float a, float b) {
    unsigned r;
    asm("v_cvt_pk_bf16_f32 %0, %1, %2" : "=v"(r) : "v"(a), "v"(b));
    return r;   // lo = bf16(a), hi = bf16(b), RNE
}
static __device__ __forceinline__ void unpk2(int u, float& lo, float& hi) {
    union { unsigned u; float f; } a, b;
    a.u = ((unsigned)u) << 16;
    b.u = ((unsigned)u) & 0xffff0000u;
    lo = a.f; hi = b.f;
}

// ---------------- kernel 1: weights f32 -> bf16 ----------------
struct WSrc { const float* w[8]; };

__global__ __launch_bounds__(256) void k_w2bf(WSrc src, short* wbf) {
    int t  = blockIdx.x * 256 + threadIdx.x;   // 131072 threads, 4 elems each
    int e4 = t * 4;
    int mi = e4 >> 16; int off = e4 & 65535;
    f32x4 v = *(const f32x4*)(src.w[mi] + off);
    s16x4 o;
    o[0] = f2bf(v[0]); o[1] = f2bf(v[1]); o[2] = f2bf(v[2]); o[3] = f2bf(v[3]);
    *(s16x4*)(wbf + mi * 65536 + off) = o;
}

// ---------------- kernel 2: QKV projections (+ fused row-norms) ----------------
// bz: 0 mq, 1 mk, 2 mv(->mvT), 3 sq=sqrt(elu+1), 4 sk, 5 cv=elu+1(->cvT)
// psums: [4][PSN] f32 row-norms: 0:||mq||^2  1:||mk||^2  2:||sq||^2  3:||sk||^2
struct BiasP { const float* b[6]; };

__global__ __launch_bounds__(256) void k_proj(const float* Xmean, const float* Xcov,
                                              const short* wbf, BiasP bp,
                                              short* mq, short* mk, short* sq, short* sk,
                                              short* mvT, short* cvT, float* psums) {
    const int bz = blockIdx.z;
    const float* X = (bz < 3) ? Xmean : Xcov;
    const short* W = wbf + bz * 65536;
    const float* bias = bp.b[bz];
    const int m0 = blockIdx.x * 64, n0 = blockIdx.y * 64;
    const int tid = threadIdx.x, wv = tid >> 6, l = tid & 63;

    __shared__ __align__(16) short x_l[64][40];   // 32 used + pad
    __shared__ __align__(16) short w_l[64][40];
    __shared__ __align__(16) short t_l[64][65];   // transpose staging (odd stride)

    f32x4 zero4 = {0.f, 0.f, 0.f, 0.f};
    f32x4 acc[4] = {zero4, zero4, zero4, zero4};

    for (int kk = 0; kk < 8; kk++) {
        const int k0 = kk * 32;
        #pragma unroll
        for (int i = 0; i < 2; i++) {               // X tile: 64x32 f32 -> bf16
            int g = tid + i * 256; int mr = g >> 3, ci = g & 7;
            f32x4 xv = *(const f32x4*)(X + (size_t)(m0 + mr) * HID_ + k0 + ci * 4);
            s16x4 xs; xs[0] = f2bf(xv[0]); xs[1] = f2bf(xv[1]); xs[2] = f2bf(xv[2]); xs[3] = f2bf(xv[3]);
            *(s16x4*)&x_l[mr][ci * 4] = xs;
        }
        {                                            // W tile: 64x32 bf16
            int o = tid >> 2, ci = tid & 3;
            *(s16x8*)&w_l[o][ci * 8] = *(const s16x8*)(W + (n0 + o) * HID_ + k0 + ci * 8);
        }
        __syncthreads();
        s16x8 a = *(const s16x8*)&x_l[wv * 16 + (l & 15)][8 * (l >> 4)];
        #pragma unroll
        for (int nt = 0; nt < 4; nt++) {
            s16x8 b = *(const s16x8*)&w_l[nt * 16 + (l & 15)][8 * (l >> 4)];
            MFMA16(acc[nt], a, b);
        }
        __syncthreads();
    }

    const bool tr = (bz == 2 || bz == 5);
    const int bb = m0 >> 9;          // batch
    const int s0 = m0 & 511;         // seq base
    const int h  = blockIdx.y;       // head (BN=64 == DH)
    short* dstd = (bz == 0) ? mq : (bz == 1) ? mk : (bz == 3) ? sq : sk;

    float ps[4] = {0.f, 0.f, 0.f, 0.f};  // per-r row-norm partials

    #pragma unroll
    for (int nt = 0; nt < 4; nt++) {
        #pragma unroll
        for (int r = 0; r < 4; r++) {
            int ml = wv * 16 + 4 * (l >> 4) + r;
            int ol = nt * 16 + (l & 15);
            float val = acc[nt][r] + bias[n0 + ol];
            if (bz == 3 || bz == 4) {
                float e1 = (val > 0.f) ? val + 1.f : __expf(val);
                e1 = fmaxf(e1, 1e-24f);
                ps[r] += e1;                       // ||sqrt(e1)||^2 contribution
                val = sqrtf(e1);
            } else if (bz == 5) {
                val = (val > 0.f) ? val + 1.f : __expf(val);
            } else if (bz != 2) {
                ps[r] += val * val;                // ||mq||^2 / ||mk||^2
            }
            short bfv = f2bf(val);
            if (tr) t_l[ml][ol] = bfv;
            else    dstd[(((size_t)(bb * NH_ + h) * S_ + (s0 + ml)) * DH_) + ol] = bfv;
        }
    }
    if (bz != 2 && bz != 5) {
        const int aidx = (bz == 0) ? 0 : (bz == 1) ? 1 : (bz == 3) ? 2 : 3;
        float* PS = psums + (size_t)aidx * PSN;
        #pragma unroll
        for (int r = 0; r < 4; r++) {
            float s = ps[r];
            s += __shfl_xor(s, 1); s += __shfl_xor(s, 2);
            s += __shfl_xor(s, 4); s += __shfl_xor(s, 8);
            if ((l & 15) == 0) {
                int ml = wv * 16 + 4 * (l >> 4) + r;
                PS[(size_t)(bb * NH_ + h) * S_ + (s0 + ml)] = s;
            }
        }
    }
    if (tr) {
        __syncthreads();
        short* dst = (bz == 2) ? mvT : cvT;
        #pragma unroll
        for (int i = 0; i < 2; i++) {
            int g = tid + i * 256; int orow = g >> 3, ci = g & 7;
            s16x8 v;
            #pragma unroll
            for (int j = 0; j < 8; j++) v[j] = t_l[ci * 8 + j][orow];
            *(s16x8*)(dst + ((size_t)(bb * NH_ + h) * DH_ + orow) * S_ + s0 + ci * 8) = v;
        }
    }
}

// ---------------- kernel 3: fused Wasserstein attention (v2) ----------------
// No LDS staging in main loops. QK: K-fragments direct from global (coalesced
// 16 rows x 64B), barrier-free. P kept in regs; transposed to PV A-layout via
// 8x ds_bpermute per K-tile; probs written straight from the A-frags; P^2
// squared once per element. PV: B = V^T direct from global. Cross-wave work:
// rowsum (256B LDS) + 16KB f32 ctx reduction. 3 barriers total.
__global__ __launch_bounds__(256, 4) void k_attn(const short* mq, const short* mk,
                                                 const short* sq, const short* sk,
                                                 const short* mvT, const short* cvT,
                                                 const float* psums,
                                                 const float* mask, float* probs,
                                                 short* mctx, short* cctx) {
    const int vb = (blockIdx.x & 7) * 512 + (blockIdx.x >> 3);   // XCD grouping
    const int bh = vb >> 4, qb = vb & 15;
    const int b = bh >> 2, h = bh & 3;
    const int q0 = qb * 32;
    const int tid = threadIdx.x, w = tid >> 6, l = tid & 63;
    const int mt = w & 1, kq = w >> 1;        // q-tile (16 rows), k-half (256 k)
    const int lg = l >> 4, lr = l & 15;

    __shared__ __align__(16) float red[2][32][65];   // 16640B ctx partial (pad 65: no conflicts)
    __shared__ __align__(16) short obuf[2][32][72];  // 9216B bf16 out staging (144B rows)
    __shared__ float rsum_l[32][2];

    // --- Q fragments + row norm ---
    const int qrow = q0 + mt * 16 + lr;
    const size_t qoff = (size_t)bh * S_ + qrow;
    const short* mqR = mq + qoff * DH_;
    const short* sqR = sq + qoff * DH_;
    s16x8 qm0 = *(const s16x8*)(mqR + 8 * lg);
    s16x8 qm1 = *(const s16x8*)(mqR + 32 + 8 * lg);
    s16x8 qv0 = *(const s16x8*)(sqR + 8 * lg);
    s16x8 qv1 = *(const s16x8*)(sqR + 32 + 8 * lg);
    const float qsv = psums[qoff] + psums[2 * (size_t)PSN + qoff];

    const short* mkB = mk + (size_t)bh * (S_ * DH_);
    const short* skB = sk + (size_t)bh * (S_ * DH_);
    const float* ksMB = psums + 1 * (size_t)PSN + bh * S_;
    const float* ksSB = psums + 3 * (size_t)PSN + bh * S_;
    const float* maskR = mask + (size_t)b * (S_ * S_) + (size_t)qrow * S_;

    // ---- QK phase: barrier-free, K-frags from global ----
    s16x4 pb[8][2];          // lane holds P[k = base+4*lg+r][q = qrow]
    float rs = 0.f;
    #pragma unroll
    for (int kt = 0; kt < 8; kt++) {
        #pragma unroll
        for (int nn = 0; nn < 2; nn++) {
            const int krl = kt * 64 + kq * 32 + nn * 16 + lr;    // A-frag k-row
            const short* kmp = mkB + krl * 64;
            const short* ksp = skB + krl * 64;
            s16x8 am0 = *(const s16x8*)(kmp + 8 * lg);
            s16x8 am1 = *(const s16x8*)(kmp + 32 + 8 * lg);
            s16x8 as0 = *(const s16x8*)(ksp + 8 * lg);
            s16x8 as1 = *(const s16x8*)(ksp + 32 + 8 * lg);
            const int kbase = kt * 64 + kq * 32 + nn * 16 + 4 * lg;
            f32x4 kvM = *(const f32x4*)(ksMB + kbase);
            f32x4 kvS = *(const f32x4*)(ksSB + kbase);
            f32x4 mkv = *(const f32x4*)(maskR + kbase);
            f32x4 acc = {0.f, 0.f, 0.f, 0.f};
            MFMA16(acc, am0, qm0); MFMA16(acc, am1, qm1);
            MFMA16(acc, as0, qv0); MFMA16(acc, as1, qv1);
            float p[4];
            #pragma unroll
            for (int r = 0; r < 4; r++) {
                float kvq = qsv + kvM[r] + kvS[r];
                float dist = kvq - 2.f * acc[r];
                float t = __expf(-dist) * 0.125f;
                float pp = __expf(t + mkv[r]);      // scores tiny: no max-subtract
                rs += pp; p[r] = pp;
            }
            union { unsigned u[2]; s16x4 v; } pk;
            pk.u[0] = cvt_pk_bf16(p[0], p[1]);
            pk.u[1] = cvt_pk_bf16(p[2], p[3]);
            pb[kt][nn] = pk.v;
        }
    }

    // ---- row sums (barrier 1) ----
    rs += __shfl_xor(rs, 16); rs += __shfl_xor(rs, 32);
    if (l < 16) rsum_l[mt * 16 + l][kq] = rs;
    __syncthreads();
    const float rvp = 1.f / (rsum_l[mt * 16 + lr][0] + rsum_l[mt * 16 + lr][1]);

    // ---- PV phase: barrier-free ----
    // A-frag build: target lane (lg,lr) needs P[k=8*lg+j][q=lr] within the
    // 32-k chunk: tile nn = lg>>1, source lanes (2*(lg&1), lr) and (+16, lr).
    const int src0 = ((lg & 1) * 32 + lr) * 4;   // byte lane-addr for bpermute
    const int src1 = src0 + 64;
    const bool hi = (l & 32) != 0;               // lg>>1
    const short* mvB = mvT + (size_t)bh * (DH_ * S_);
    const short* cvB = cvT + (size_t)bh * (DH_ * S_);
    float* probsR = probs + (size_t)bh * (S_ * S_) + (size_t)qrow * S_ + kq * 32 + 8 * lg;

    f32x4 zero4 = {0.f, 0.f, 0.f, 0.f};
    f32x4 cm[4] = {zero4, zero4, zero4, zero4};  // ctx[q=mt*16+4lg+r][d=dt*16+lr]
    f32x4 cc[4] = {zero4, zero4, zero4, zero4};

    #pragma unroll
    for (int kt = 0; kt < 8; kt++) {
        union { s16x4 v; int i[2]; } p0, p1;
        p0.v = pb[kt][0]; p1.v = pb[kt][1];
        int b00 = __builtin_amdgcn_ds_bpermute(src0, p0.i[0]);
        int b01 = __builtin_amdgcn_ds_bpermute(src0, p0.i[1]);
        int b10 = __builtin_amdgcn_ds_bpermute(src0, p1.i[0]);
        int b11 = __builtin_amdgcn_ds_bpermute(src0, p1.i[1]);
        int c00 = __builtin_amdgcn_ds_bpermute(src1, p0.i[0]);
        int c01 = __builtin_amdgcn_ds_bpermute(src1, p0.i[1]);
        int c10 = __builtin_amdgcn_ds_bpermute(src1, p1.i[0]);
        int c11 = __builtin_amdgcn_ds_bpermute(src1, p1.i[1]);
        union { int i[4]; s16x8 v; } af, af2;
        af.i[0] = hi ? b10 : b00;   // j=0,1
        af.i[1] = hi ? b11 : b01;   // j=2,3
        af.i[2] = hi ? c10 : c00;   // j=4,5
        af.i[3] = hi ? c11 : c01;   // j=6,7

        float f0,f1,f2,f3,f4,f5,f6,f7;
        unpk2(af.i[0], f0, f1); unpk2(af.i[1], f2, f3);
        unpk2(af.i[2], f4, f5); unpk2(af.i[3], f6, f7);

        // probs straight from A-frag: 8 consecutive k per lane
        f32x4 o0 = {f0 * rvp, f1 * rvp, f2 * rvp, f3 * rvp};
        f32x4 o1 = {f4 * rvp, f5 * rvp, f6 * rvp, f7 * rvp};
        *(f32x4*)(probsR + kt * 64)     = o0;
        *(f32x4*)(probsR + kt * 64 + 4) = o1;

        // P^2, squared once per element
        af2.i[0] = (int)cvt_pk_bf16(f0 * f0, f1 * f1);
        af2.i[1] = (int)cvt_pk_bf16(f2 * f2, f3 * f3);
        af2.i[2] = (int)cvt_pk_bf16(f4 * f4, f5 * f5);
        af2.i[3] = (int)cvt_pk_bf16(f6 * f6, f7 * f7);

        const int kb2 = kt * 64 + kq * 32 + 8 * lg;
        #pragma unroll
        for (int dt = 0; dt < 4; dt++) {
            const size_t boff = (size_t)(dt * 16 + lr) * S_ + kb2;
            s16x8 bm = *(const s16x8*)(mvB + boff);   // B[k][d]: V^T rows
            s16x8 bc = *(const s16x8*)(cvB + boff);
            MFMA16(cm[dt], af.v, bm);
            MFMA16(cc[dt], af2.v, bc);
        }
    }

    // ---- ctx cross-wave (kq) reduction + epilogue ----
    if (kq == 0) {
        #pragma unroll
        for (int dt = 0; dt < 4; dt++)
            #pragma unroll
            for (int r = 0; r < 4; r++) {
                red[0][mt * 16 + 4 * lg + r][dt * 16 + lr] = cm[dt][r];
                red[1][mt * 16 + 4 * lg + r][dt * 16 + lr] = cc[dt][r];
            }
    }
    __syncthreads();                                  // barrier 2
    if (kq == 1) {
        #pragma unroll
        for (int r = 0; r < 4; r++) {
            const int row = mt * 16 + 4 * lg + r;
            const float rv = 1.f / (rsum_l[row][0] + rsum_l[row][1]);
            #pragma unroll
            for (int dt = 0; dt < 4; dt++) {
                float vm = (red[0][row][dt * 16 + lr] + cm[dt][r]) * rv;
                float vc = (red[1][row][dt * 16 + lr] + cc[dt][r]) * rv * rv;
                obuf[0][row][dt * 16 + lr] = f2bf(vm);
                obuf[1][row][dt * 16 + lr] = f2bf(vc);
            }
        }
    }
    __syncthreads();                                  // barrier 3
    {
        const int row = tid >> 3, pc = tid & 7;
        s16x8 vm = *(const s16x8*)&obuf[0][row][pc * 8];
        s16x8 vc = *(const s16x8*)&obuf[1][row][pc * 8];
        size_t base = ((size_t)(b * S_ + q0 + row)) * HID_ + h * DH_ + pc * 8;
        *(s16x8*)(mctx + base) = vm;
        *(s16x8*)(cctx + base) = vc;
    }
}

// ---------------- kernel 4: output dense + residual + LayerNorm ----------------
__global__ __launch_bounds__(256) void k_final(const short* mctx, const short* cctx,
                                               const short* wbf,
                                               const float* bmd, const float* bcd,
                                               const float* Xmean, const float* Xcov,
                                               const float* lnw, const float* lnb,
                                               float* outbase) {
    const int which = blockIdx.y;
    const short* C = which ? cctx : mctx;
    const short* W = wbf + (6 + which) * 65536;
    const float* bias = which ? bcd : bmd;
    const float* X = which ? Xcov : Xmean;
    float* out = outbase + (size_t)which * MEANH_ELEMS;

    const int m0 = blockIdx.x * 32;
    const int tid = threadIdx.x, wv = tid >> 6, l = tid & 63;

    __shared__ __align__(16) short c_l[32][40];
    __shared__ __align__(16) short w_l[256][40];
    __shared__ float h_l[32][256];

    f32x4 zero4 = {0.f, 0.f, 0.f, 0.f};
    f32x4 acc[2][4];
    #pragma unroll
    for (int mtI = 0; mtI < 2; mtI++)
        #pragma unroll
        for (int nt = 0; nt < 4; nt++) acc[mtI][nt] = zero4;

    for (int kk = 0; kk < 8; kk++) {
        const int k0 = kk * 32;
        if (tid < 128) {
            int row = tid >> 2, ci = tid & 3;
            *(s16x8*)&c_l[row][ci * 8] = *(const s16x8*)(C + (size_t)(m0 + row) * HID_ + k0 + ci * 8);
        }
        #pragma unroll
        for (int i = 0; i < 4; i++) {
            int g = tid + i * 256; int o = g >> 2, ci = g & 3;
            *(s16x8*)&w_l[o][ci * 8] = *(const s16x8*)(W + o * HID_ + k0 + ci * 8);
        }
        __syncthreads();
        s16x8 a[2];
        #pragma unroll
        for (int mtI = 0; mtI < 2; mtI++)
            a[mtI] = *(const s16x8*)&c_l[mtI * 16 + (l & 15)][8 * (l >> 4)];
        #pragma unroll
        for (int nt = 0; nt < 4; nt++) {
            s16x8 bfr = *(const s16x8*)&w_l[wv * 64 + nt * 16 + (l & 15)][8 * (l >> 4)];
            MFMA16(acc[0][nt], a[0], bfr);
            MFMA16(acc[1][nt], a[1], bfr);
        }
        __syncthreads();
    }
    #pragma unroll
    for (int mtI = 0; mtI < 2; mtI++) {
        #pragma unroll
        for (int nt = 0; nt < 4; nt++) {
            #pragma unroll
            for (int r = 0; r < 4; r++) {
                int ml = mtI * 16 + 4 * (l >> 4) + r;
                int o = wv * 64 + nt * 16 + (l & 15);
                h_l[ml][o] = acc[mtI][nt][r] + bias[o] + X[(size_t)(m0 + ml) * HID_ + o];
            }
        }
    }
    __syncthreads();
    // LayerNorm: each wave owns 8 rows
    #pragma unroll
    for (int i = 0; i < 8; i++) {
        int row = wv * 8 + i;
        float s = 0.f;
        #pragma unroll
        for (int c = 0; c < 4; c++) s += h_l[row][l + c * 64];
        #pragma unroll
        for (int m = 1; m < 64; m <<= 1) s += __shfl_xor(s, m);
        float u = s * (1.f / 256.f);
        float s2 = 0.f;
        #pragma unroll
        for (int c = 0; c < 4; c++) { float d = h_l[row][l + c * 64] - u; s2 += d * d; }
        #pragma unroll
        for (int m = 1; m < 64; m <<= 1) s2 += __shfl_xor(s2, m);
        float rstd = rsqrtf(s2 * (1.f / 256.f) + 1e-12f);
        #pragma unroll
        for (int c = 0; c < 4; c++) {
            int o = l + c * 64;
            out[(size_t)(m0 + row) * HID_ + o] = lnw[o] * ((h_l[row][o] - u) * rstd) + lnb[o];
        }
    }
}

// ---------------- host ----------------
extern "C" void kernel_launch(void* const* d_in, const int* in_sizes, int n_in,
                              void* d_out, int out_size, void* d_ws, size_t ws_size,
                              hipStream_t stream) {
    const float* x_mean = (const float*)d_in[0];
    const float* x_cov  = (const float*)d_in[1];
    const float* mask   = (const float*)d_in[2];
    // weight order in wbf: Wmq Wmk Wmv Wcq Wck Wcv Wmd Wcd
    WSrc src;
    src.w[0] = (const float*)d_in[3];  src.w[1] = (const float*)d_in[5];
    src.w[2] = (const float*)d_in[7];  src.w[3] = (const float*)d_in[9];
    src.w[4] = (const float*)d_in[11]; src.w[5] = (const float*)d_in[13];
    src.w[6] = (const float*)d_in[15]; src.w[7] = (const float*)d_in[17];
    BiasP bp;
    bp.b[0] = (const float*)d_in[4];  bp.b[1] = (const float*)d_in[6];
    bp.b[2] = (const float*)d_in[8];  bp.b[3] = (const float*)d_in[10];
    bp.b[4] = (const float*)d_in[12]; bp.b[5] = (const float*)d_in[14];
    const float* bmd = (const float*)d_in[16];
    const float* bcd = (const float*)d_in[18];
    const float* lnw = (const float*)d_in[19];
    const float* lnb = (const float*)d_in[20];
    float* out = (float*)d_out;

    char* wsb = (char*)d_ws;
    short* wbf = (short*)wsb;                       // 8*65536*2 = 1 MiB
    short* mq  = (short*)(wsb + (1 << 20));
    short* mk  = mq  + TSZ;
    short* sq  = mk  + TSZ;
    short* sk  = sq  + TSZ;
    short* mvT = sk  + TSZ;
    short* cvT = mvT + TSZ;
    float* psums = (float*)(cvT + TSZ);             // 4 * 131072 f32 = 2 MiB
    short* mctx = (short*)(psums + 4 * (size_t)PSN);
    short* cctx = mctx + TSZ;

    float* probs = out + PROBS_OFF;

    hipLaunchKernelGGL(k_w2bf, dim3(512), dim3(256), 0, stream, src, wbf);
    hipLaunchKernelGGL(k_proj, dim3(512, 4, 6), dim3(256), 0, stream,
                       x_mean, x_cov, wbf, bp, mq, mk, sq, sk, mvT, cvT, psums);
    hipLaunchKernelGGL(k_attn, dim3(BH_ * 16), dim3(256), 0, stream,
                       mq, mk, sq, sk, mvT, cvT, psums, mask, probs, mctx, cctx);
    hipLaunchKernelGGL(k_final, dim3(BS_ / 32, 2), dim3(256), 0, stream,
                       mctx, cctx, wbf, bmd, bcd, x_mean, x_cov, lnw, lnb, out);
}

// Round 3
// 449.214 us; speedup vs baseline: 1.0921x; 1.0921x over previous
//
#include <hip/hip_runtime.h>
#include <math.h>

// ---------------- problem constants ----------------
#define B_    64
#define S_    512
#define HID_  256
#define NH_   4
#define DH_   64
#define BH_   (B_*NH_)            // 256 head-batches
#define BS_   (B_*S_)             // 32768 rows
#define TSZ   (BH_*S_*DH_)        // 8,388,608 bf16 elems per projected tensor
#define PSN   (BH_*S_)            // 131072 rows (per-head row-norm arrays)
#define MEANH_ELEMS (BS_*HID_)    // 8,388,608
#define PROBS_OFF   (2*MEANH_ELEMS)

typedef __attribute__((ext_vector_type(8))) short s16x8;
typedef __attribute__((ext_vector_type(4))) short s16x4;
typedef __attribute__((ext_vector_type(4))) float f32x4;

#define MFMA16(acc, a, b) (acc) = __builtin_amdgcn_mfma_f32_16x16x32_bf16((a), (b), (acc), 0, 0, 0)

static __device__ __forceinline__ short f2bf(float f) {
    union { float f; unsigned u; } a; a.f = f;
    unsigned r = a.u + 0x7fffu + ((a.u >> 16) & 1u);   // RNE
    return (short)(r >> 16);
}
static __device__ __forceinline__ float b2f(short s) {
    union { unsigned u; float f; } a; a.u = ((unsigned)(unsigned short)s) << 16;
    return a.f;
}
static __device__ __forceinline__ unsigned cvt_pk_bf16(float a, float b) {
    unsigned r;
    asm("v_cvt_pk_bf16_f32 %0, %1, %2" : "=v"(r) : "v"(a), "v"(b));
    return r;   // lo = bf16(a), hi = bf16(b), RNE
}
static __device__ __forceinline__ void unpk2(int u, float& lo, float& hi) {
    union { unsigned u; float f; } a, b;
    a.u = ((unsigned)u) << 16;
    b.u = ((unsigned)u) & 0xffff0000u;
    lo = a.f; hi = b.f;
}

// ---------------- kernel 1: weights f32 -> bf16 ----------------
struct WSrc { const float* w[8]; };

__global__ __launch_bounds__(256) void k_w2bf(WSrc src, short* wbf) {
    int t  = blockIdx.x * 256 + threadIdx.x;   // 131072 threads, 4 elems each
    int e4 = t * 4;
    int mi = e4 >> 16; int off = e4 & 65535;
    f32x4 v = *(const f32x4*)(src.w[mi] + off);
    s16x4 o;
    o[0] = f2bf(v[0]); o[1] = f2bf(v[1]); o[2] = f2bf(v[2]); o[3] = f2bf(v[3]);
    *(s16x4*)(wbf + mi * 65536 + off) = o;
}

// ---------------- kernel 2: QKV projections (+ fused row-norms) ----------------
// bz: 0 mq, 1 mk, 2 mv(->mvT), 3 sq=sqrt(elu+1), 4 sk, 5 cv=elu+1(->cvT)
// psums: [4][PSN] f32 row-norms of the STORED bf16 values (matches k_rowsum numerics):
//   0:||mq||^2  1:||mk||^2  2:||sq||^2  3:||sk||^2
struct BiasP { const float* b[6]; };

__global__ __launch_bounds__(256) void k_proj(const float* Xmean, const float* Xcov,
                                              const short* wbf, BiasP bp,
                                              short* mq, short* mk, short* sq, short* sk,
                                              short* mvT, short* cvT, float* psums) {
    const int bz = blockIdx.z;
    const float* X = (bz < 3) ? Xmean : Xcov;
    const short* W = wbf + bz * 65536;
    const float* bias = bp.b[bz];
    const int m0 = blockIdx.x * 64, n0 = blockIdx.y * 64;
    const int tid = threadIdx.x, wv = tid >> 6, l = tid & 63;

    __shared__ __align__(16) short x_l[64][40];   // 32 used + pad
    __shared__ __align__(16) short w_l[64][40];
    __shared__ __align__(16) short t_l[64][65];   // transpose staging (odd stride)

    f32x4 zero4 = {0.f, 0.f, 0.f, 0.f};
    f32x4 acc[4] = {zero4, zero4, zero4, zero4};

    for (int kk = 0; kk < 8; kk++) {
        const int k0 = kk * 32;
        #pragma unroll
        for (int i = 0; i < 2; i++) {               // X tile: 64x32 f32 -> bf16
            int g = tid + i * 256; int mr = g >> 3, ci = g & 7;
            f32x4 xv = *(const f32x4*)(X + (size_t)(m0 + mr) * HID_ + k0 + ci * 4);
            s16x4 xs; xs[0] = f2bf(xv[0]); xs[1] = f2bf(xv[1]); xs[2] = f2bf(xv[2]); xs[3] = f2bf(xv[3]);
            *(s16x4*)&x_l[mr][ci * 4] = xs;
        }
        {                                            // W tile: 64x32 bf16
            int o = tid >> 2, ci = tid & 3;
            *(s16x8*)&w_l[o][ci * 8] = *(const s16x8*)(W + (n0 + o) * HID_ + k0 + ci * 8);
        }
        __syncthreads();
        s16x8 a = *(const s16x8*)&x_l[wv * 16 + (l & 15)][8 * (l >> 4)];
        #pragma unroll
        for (int nt = 0; nt < 4; nt++) {
            s16x8 b = *(const s16x8*)&w_l[nt * 16 + (l & 15)][8 * (l >> 4)];
            MFMA16(acc[nt], a, b);
        }
        __syncthreads();
    }

    const bool tr = (bz == 2 || bz == 5);
    const int bb = m0 >> 9;          // batch
    const int s0 = m0 & 511;         // seq base
    const int h  = blockIdx.y;       // head (BN=64 == DH)
    short* dstd = (bz == 0) ? mq : (bz == 1) ? mk : (bz == 3) ? sq : sk;

    float ps[4] = {0.f, 0.f, 0.f, 0.f};  // per-r row-norm partials (of stored bf16)

    #pragma unroll
    for (int nt = 0; nt < 4; nt++) {
        #pragma unroll
        for (int r = 0; r < 4; r++) {
            int ml = wv * 16 + 4 * (l >> 4) + r;
            int ol = nt * 16 + (l & 15);
            float val = acc[nt][r] + bias[n0 + ol];
            if (bz == 3 || bz == 4) {
                float e1 = (val > 0.f) ? val + 1.f : __expf(val);
                val = sqrtf(fmaxf(e1, 1e-24f));
            } else if (bz == 5) {
                val = (val > 0.f) ? val + 1.f : __expf(val);
            }
            short bfv = f2bf(val);
            if (bz == 0 || bz == 1 || bz == 3 || bz == 4) {
                float qv = b2f(bfv);          // norm of the bf16-rounded value
                ps[r] += qv * qv;
            }
            if (tr) t_l[ml][ol] = bfv;
            else    dstd[(((size_t)(bb * NH_ + h) * S_ + (s0 + ml)) * DH_) + ol] = bfv;
        }
    }
    if (bz != 2 && bz != 5) {
        const int aidx = (bz == 0) ? 0 : (bz == 1) ? 1 : (bz == 3) ? 2 : 3;
        float* PS = psums + (size_t)aidx * PSN;
        #pragma unroll
        for (int r = 0; r < 4; r++) {
            float s = ps[r];
            s += __shfl_xor(s, 1); s += __shfl_xor(s, 2);
            s += __shfl_xor(s, 4); s += __shfl_xor(s, 8);
            if ((l & 15) == 0) {
                int ml = wv * 16 + 4 * (l >> 4) + r;
                PS[(size_t)(bb * NH_ + h) * S_ + (s0 + ml)] = s;
            }
        }
    }
    if (tr) {
        __syncthreads();
        short* dst = (bz == 2) ? mvT : cvT;
        #pragma unroll
        for (int i = 0; i < 2; i++) {
            int g = tid + i * 256; int orow = g >> 3, ci = g & 7;
            s16x8 v;
            #pragma unroll
            for (int j = 0; j < 8; j++) v[j] = t_l[ci * 8 + j][orow];
            *(s16x8*)(dst + ((size_t)(bb * NH_ + h) * DH_ + orow) * S_ + s0 + ci * 8) = v;
        }
    }
}

// ---------------- kernel 3: fused Wasserstein attention (v4) ----------------
// QK: single-buffered LDS K staging, strict 2-barrier protocol per tile
// (no concurrent write-while-read); next tile's global loads in flight across
// the compute phase. P transposed to PV A-layout per tile via ds_bpermute
// (v2-validated code). PV: single pass, V^T loads hoisted to iteration top
// (named regs, no pointer-indexed buffers); probs from regs; P^2 once.
// Epilogue: v2's red/obuf scheme; obuf overlays kbuf (kbuf dead after rowsum
// barrier). LDS 35328B -> 4 blocks/CU.
__global__ __launch_bounds__(256, 4) void k_attn(const short* mq, const short* mk,
                                                 const short* sq, const short* sk,
                                                 const short* mvT, const short* cvT,
                                                 const float* psums,
                                                 const float* mask, float* probs,
                                                 short* mctx, short* cctx) {
    const int vb = (blockIdx.x & 7) * 512 + (blockIdx.x >> 3);   // XCD grouping
    const int bh = vb >> 4, qb = vb & 15;
    const int b = bh >> 2, h = bh & 3;
    const int q0 = qb * 32;
    const int tid = threadIdx.x, w = tid >> 6, l = tid & 63;
    const int mt = w & 1, kq = w >> 1;        // q-tile (16 rows), k-half (256 k)
    const int lg = l >> 4, lr = l & 15;

    __shared__ __align__(16) short kbuf[2][64][72];   // 18432B (QK); obuf overlay (epilogue)
    __shared__ __align__(16) float red[2][32][65];    // 16640B ctx partials
    __shared__ float rsum_l[32][2];

    // --- Q fragments + row norm (precomputed from bf16-rounded values) ---
    const int qrow = q0 + mt * 16 + lr;
    const size_t qoff = (size_t)bh * S_ + qrow;
    const short* mqR = mq + qoff * DH_;
    const short* sqR = sq + qoff * DH_;
    s16x8 qm0 = *(const s16x8*)(mqR + 8 * lg);
    s16x8 qm1 = *(const s16x8*)(mqR + 32 + 8 * lg);
    s16x8 qv0 = *(const s16x8*)(sqR + 8 * lg);
    s16x8 qv1 = *(const s16x8*)(sqR + 32 + 8 * lg);
    const float qsv = psums[qoff] + psums[2 * (size_t)PSN + qoff];

    const short* mkB = mk + (size_t)bh * (S_ * DH_);
    const short* skB = sk + (size_t)bh * (S_ * DH_);
    const float* ksMB = psums + 1 * (size_t)PSN + bh * S_;
    const float* ksSB = psums + 3 * (size_t)PSN + bh * S_;
    const float* maskR = mask + (size_t)b * (S_ * S_) + (size_t)qrow * S_;

    // K staging regs (single LDS buffer, 2-barrier protocol)
    const int srow = tid >> 3, sci = (tid & 7) * 8;
    s16x8 Rm[2], Rs[2];
    auto ldK = [&](int kt) {
        #pragma unroll
        for (int i = 0; i < 2; i++) {
            int row = kt * 64 + srow + i * 32;
            Rm[i] = *(const s16x8*)(mkB + row * 64 + sci);
            Rs[i] = *(const s16x8*)(skB + row * 64 + sci);
        }
    };
    auto wrK = [&]() {
        #pragma unroll
        for (int i = 0; i < 2; i++) {
            *(s16x8*)&kbuf[0][srow + i * 32][sci] = Rm[i];
            *(s16x8*)&kbuf[1][srow + i * 32][sci] = Rs[i];
        }
    };

    // transpose constants (v2-validated): target lane (lg,lr) takes
    // P[k=8*lg+j][q=lr] of the 32-k chunk from source lanes
    // (2*(lg&1)+{0,1}, lr) [lo half] and (+16) [hi half], selected by l>=32.
    const int src0 = ((lg & 1) * 32 + lr) * 4;   // byte lane-addr for bpermute
    const int src1 = src0 + 64;
    const bool hi = (l & 32) != 0;

    ldK(0);
    int afA[8][4];           // P in PV A-frag layout (bf16 packed), per k-tile
    float rs = 0.f;
    #pragma unroll
    for (int kt = 0; kt < 8; kt++) {
        if (kt > 0) __syncthreads();      // (a) all reads of previous tile done
        wrK();
        __syncthreads();                  // (b) writes visible
        if (kt < 7) ldK(kt + 1);          // in flight across the compute phase
        s16x4 pb0, pb1;
        #pragma unroll
        for (int nn = 0; nn < 2; nn++) {
            const int krl = kq * 32 + nn * 16 + lr;
            s16x8 am0 = *(const s16x8*)&kbuf[0][krl][8 * lg];
            s16x8 am1 = *(const s16x8*)&kbuf[0][krl][32 + 8 * lg];
            s16x8 as0 = *(const s16x8*)&kbuf[1][krl][8 * lg];
            s16x8 as1 = *(const s16x8*)&kbuf[1][krl][32 + 8 * lg];
            const int kbase = kt * 64 + kq * 32 + nn * 16 + 4 * lg;
            f32x4 kvM = *(const f32x4*)(ksMB + kbase);
            f32x4 kvS = *(const f32x4*)(ksSB + kbase);
            f32x4 mkv = *(const f32x4*)(maskR + kbase);
            f32x4 acc = {0.f, 0.f, 0.f, 0.f};
            MFMA16(acc, am0, qm0); MFMA16(acc, am1, qm1);
            MFMA16(acc, as0, qv0); MFMA16(acc, as1, qv1);
            float p[4];
            #pragma unroll
            for (int r = 0; r < 4; r++) {
                float dist = qsv + kvM[r] + kvS[r] - 2.f * acc[r];
                float t = __expf(-dist) * 0.125f;
                float pp = __expf(t + mkv[r]);      // scores tiny: no max-subtract
                rs += pp; p[r] = pp;
            }
            union { unsigned u[2]; s16x4 v; } pk;
            pk.u[0] = cvt_pk_bf16(p[0], p[1]);
            pk.u[1] = cvt_pk_bf16(p[2], p[3]);
            if (nn == 0) pb0 = pk.v; else pb1 = pk.v;
        }
        // in-register transpose of this tile's P (v2-validated)
        {
            union { s16x4 v; int i[2]; } p0, p1;
            p0.v = pb0; p1.v = pb1;
            int b00 = __builtin_amdgcn_ds_bpermute(src0, p0.i[0]);
            int b01 = __builtin_amdgcn_ds_bpermute(src0, p0.i[1]);
            int b10 = __builtin_amdgcn_ds_bpermute(src0, p1.i[0]);
            int b11 = __builtin_amdgcn_ds_bpermute(src0, p1.i[1]);
            int c00 = __builtin_amdgcn_ds_bpermute(src1, p0.i[0]);
            int c01 = __builtin_amdgcn_ds_bpermute(src1, p0.i[1]);
            int c10 = __builtin_amdgcn_ds_bpermute(src1, p1.i[0]);
            int c11 = __builtin_amdgcn_ds_bpermute(src1, p1.i[1]);
            afA[kt][0] = hi ? b10 : b00;   // j=0,1
            afA[kt][1] = hi ? b11 : b01;   // j=2,3
            afA[kt][2] = hi ? c10 : c00;   // j=4,5
            afA[kt][3] = hi ? c11 : c01;   // j=6,7
        }
    }

    // ---- row sums (kbuf reads all complete before this barrier) ----
    rs += __shfl_xor(rs, 16); rs += __shfl_xor(rs, 32);
    if (l < 16) rsum_l[mt * 16 + l][kq] = rs;
    __syncthreads();
    const float rvp = 1.f / (rsum_l[mt * 16 + lr][0] + rsum_l[mt * 16 + lr][1]);

    // ---- PV: single pass, V loads hoisted to iteration top ----
    const short* mvB = mvT + (size_t)bh * (DH_ * S_) + kq * 32 + 8 * lg;
    const short* cvB = cvT + (size_t)bh * (DH_ * S_) + kq * 32 + 8 * lg;
    float* probsR = probs + (size_t)bh * (S_ * S_) + (size_t)qrow * S_ + kq * 32 + 8 * lg;

    f32x4 zero4 = {0.f, 0.f, 0.f, 0.f};
    f32x4 cm[4] = {zero4, zero4, zero4, zero4};  // ctx[q=mt*16+4lg+r][d=dt*16+lr]
    f32x4 cc[4] = {zero4, zero4, zero4, zero4};

    #pragma unroll
    for (int kt = 0; kt < 8; kt++) {
        // hoisted V^T loads (named regs; issued before the VALU/DS work below)
        s16x8 VM0 = *(const s16x8*)(mvB + (size_t)(0 * 16 + lr) * S_ + kt * 64);
        s16x8 VM1 = *(const s16x8*)(mvB + (size_t)(1 * 16 + lr) * S_ + kt * 64);
        s16x8 VM2 = *(const s16x8*)(mvB + (size_t)(2 * 16 + lr) * S_ + kt * 64);
        s16x8 VM3 = *(const s16x8*)(mvB + (size_t)(3 * 16 + lr) * S_ + kt * 64);
        s16x8 VC0 = *(const s16x8*)(cvB + (size_t)(0 * 16 + lr) * S_ + kt * 64);
        s16x8 VC1 = *(const s16x8*)(cvB + (size_t)(1 * 16 + lr) * S_ + kt * 64);
        s16x8 VC2 = *(const s16x8*)(cvB + (size_t)(2 * 16 + lr) * S_ + kt * 64);
        s16x8 VC3 = *(const s16x8*)(cvB + (size_t)(3 * 16 + lr) * S_ + kt * 64);

        union { int i[4]; s16x8 v; } af, af2;
        af.i[0] = afA[kt][0]; af.i[1] = afA[kt][1];
        af.i[2] = afA[kt][2]; af.i[3] = afA[kt][3];
        float f0, f1, f2, f3, f4, f5, f6, f7;
        unpk2(af.i[0], f0, f1); unpk2(af.i[1], f2, f3);
        unpk2(af.i[2], f4, f5); unpk2(af.i[3], f6, f7);

        // probs straight from A-frag: 8 consecutive k per lane
        f32x4 o0 = {f0 * rvp, f1 * rvp, f2 * rvp, f3 * rvp};
        f32x4 o1 = {f4 * rvp, f5 * rvp, f6 * rvp, f7 * rvp};
        *(f32x4*)(probsR + kt * 64)     = o0;
        *(f32x4*)(probsR + kt * 64 + 4) = o1;

        // P^2, squared once per element
        af2.i[0] = (int)cvt_pk_bf16(f0 * f0, f1 * f1);
        af2.i[1] = (int)cvt_pk_bf16(f2 * f2, f3 * f3);
        af2.i[2] = (int)cvt_pk_bf16(f4 * f4, f5 * f5);
        af2.i[3] = (int)cvt_pk_bf16(f6 * f6, f7 * f7);

        MFMA16(cm[0], af.v, VM0);  MFMA16(cm[1], af.v, VM1);
        MFMA16(cm[2], af.v, VM2);  MFMA16(cm[3], af.v, VM3);
        MFMA16(cc[0], af2.v, VC0); MFMA16(cc[1], af2.v, VC1);
        MFMA16(cc[2], af2.v, VC2); MFMA16(cc[3], af2.v, VC3);
    }

    // ---- ctx cross-wave (kq) reduction + epilogue ----
    // obuf overlays kbuf: kbuf reads ended before the rowsum barrier; obuf
    // writes start after barrier-2 below. red is separate memory.
    short* obufp = (short*)kbuf;                 // [2][32][72] shorts = 9216B
    if (kq == 0) {
        #pragma unroll
        for (int dt = 0; dt < 4; dt++)
            #pragma unroll
            for (int r = 0; r < 4; r++) {
                int row = mt * 16 + 4 * lg + r;
                red[0][row][dt * 16 + lr] = cm[dt][r];
                red[1][row][dt * 16 + lr] = cc[dt][r];
            }
    }
    __syncthreads();                              // barrier-2
    if (kq == 1) {
        #pragma unroll
        for (int r = 0; r < 4; r++) {
            const int row = mt * 16 + 4 * lg + r;
            const float rv = 1.f / (rsum_l[row][0] + rsum_l[row][1]);
            #pragma unroll
            for (int dt = 0; dt < 4; dt++) {
                float vm = (red[0][row][dt * 16 + lr] + cm[dt][r]) * rv;
                float vc = (red[1][row][dt * 16 + lr] + cc[dt][r]) * rv * rv;
                obufp[row * 72 + dt * 16 + lr] = f2bf(vm);
                obufp[(32 + row) * 72 + dt * 16 + lr] = f2bf(vc);
            }
        }
    }
    __syncthreads();                              // barrier-3
    {
        const int row = tid >> 3, pc = tid & 7;
        s16x8 vm = *(const s16x8*)(obufp + row * 72 + pc * 8);
        s16x8 vc = *(const s16x8*)(obufp + (32 + row) * 72 + pc * 8);
        size_t base = ((size_t)(b * S_ + q0 + row)) * HID_ + h * DH_ + pc * 8;
        *(s16x8*)(mctx + base) = vm;
        *(s16x8*)(cctx + base) = vc;
    }
}

// ---------------- kernel 4: output dense + residual + LayerNorm ----------------
__global__ __launch_bounds__(256) void k_final(const short* mctx, const short* cctx,
                                               const short* wbf,
                                               const float* bmd, const float* bcd,
                                               const float* Xmean, const float* Xcov,
                                               const float* lnw, const float* lnb,
                                               float* outbase) {
    const int which = blockIdx.y;
    const short* C = which ? cctx : mctx;
    const short* W = wbf + (6 + which) * 65536;
    const float* bias = which ? bcd : bmd;
    const float* X = which ? Xcov : Xmean;
    float* out = outbase + (size_t)which * MEANH_ELEMS;

    const int m0 = blockIdx.x * 32;
    const int tid = threadIdx.x, wv = tid >> 6, l = tid & 63;

    __shared__ __align__(16) short c_l[32][40];
    __shared__ __align__(16) short w_l[256][40];
    __shared__ float h_l[32][256];

    f32x4 zero4 = {0.f, 0.f, 0.f, 0.f};
    f32x4 acc[2][4];
    #pragma unroll
    for (int mtI = 0; mtI < 2; mtI++)
        #pragma unroll
        for (int nt = 0; nt < 4; nt++) acc[mtI][nt] = zero4;

    for (int kk = 0; kk < 8; kk++) {
        const int k0 = kk * 32;
        if (tid < 128) {
            int row = tid >> 2, ci = tid & 3;
            *(s16x8*)&c_l[row][ci * 8] = *(const s16x8*)(C + (size_t)(m0 + row) * HID_ + k0 + ci * 8);
        }
        #pragma unroll
        for (int i = 0; i < 4; i++) {
            int g = tid + i * 256; int o = g >> 2, ci = g & 3;
            *(s16x8*)&w_l[o][ci * 8] = *(const s16x8*)(W + o * HID_ + k0 + ci * 8);
        }
        __syncthreads();
        s16x8 a[2];
        #pragma unroll
        for (int mtI = 0; mtI < 2; mtI++)
            a[mtI] = *(const s16x8*)&c_l[mtI * 16 + (l & 15)][8 * (l >> 4)];
        #pragma unroll
        for (int nt = 0; nt < 4; nt++) {
            s16x8 bfr = *(const s16x8*)&w_l[wv * 64 + nt * 16 + (l & 15)][8 * (l >> 4)];
            MFMA16(acc[0][nt], a[0], bfr);
            MFMA16(acc[1][nt], a[1], bfr);
        }
        __syncthreads();
    }
    #pragma unroll
    for (int mtI = 0; mtI < 2; mtI++) {
        #pragma unroll
        for (int nt = 0; nt < 4; nt++) {
            #pragma unroll
            for (int r = 0; r < 4; r++) {
                int ml = mtI * 16 + 4 * (l >> 4) + r;
                int o = wv * 64 + nt * 16 + (l & 15);
                h_l[ml][o] = acc[mtI][nt][r] + bias[o] + X[(size_t)(m0 + ml) * HID_ + o];
            }
        }
    }
    __syncthreads();
    // LayerNorm: each wave owns 8 rows
    #pragma unroll
    for (int i = 0; i < 8; i++) {
        int row = wv * 8 + i;
        float s = 0.f;
        #pragma unroll
        for (int c = 0; c < 4; c++) s += h_l[row][l + c * 64];
        #pragma unroll
        for (int m = 1; m < 64; m <<= 1) s += __shfl_xor(s, m);
        float u = s * (1.f / 256.f);
        float s2 = 0.f;
        #pragma unroll
        for (int c = 0; c < 4; c++) { float d = h_l[row][l + c * 64] - u; s2 += d * d; }
        #pragma unroll
        for (int m = 1; m < 64; m <<= 1) s2 += __shfl_xor(s2, m);
        float rstd = rsqrtf(s2 * (1.f / 256.f) + 1e-12f);
        #pragma unroll
        for (int c = 0; c < 4; c++) {
            int o = l + c * 64;
            out[(size_t)(m0 + row) * HID_ + o] = lnw[o] * ((h_l[row][o] - u) * rstd) + lnb[o];
        }
    }
}

// ---------------- host ----------------
extern "C" void kernel_launch(void* const* d_in, const int* in_sizes, int n_in,
                              void* d_out, int out_size, void* d_ws, size_t ws_size,
                              hipStream_t stream) {
    const float* x_mean = (const float*)d_in[0];
    const float* x_cov  = (const float*)d_in[1];
    const float* mask   = (const float*)d_in[2];
    // weight order in wbf: Wmq Wmk Wmv Wcq Wck Wcv Wmd Wcd
    WSrc src;
    src.w[0] = (const float*)d_in[3];  src.w[1] = (const float*)d_in[5];
    src.w[2] = (const float*)d_in[7];  src.w[3] = (const float*)d_in[9];
    src.w[4] = (const float*)d_in[11]; src.w[5] = (const float*)d_in[13];
    src.w[6] = (const float*)d_in[15]; src.w[7] = (const float*)d_in[17];
    BiasP bp;
    bp.b[0] = (const float*)d_in[4];  bp.b[1] = (const float*)d_in[6];
    bp.b[2] = (const float*)d_in[8];  bp.b[3] = (const float*)d_in[10];
    bp.b[4] = (const float*)d_in[12]; bp.b[5] = (const float*)d_in[14];
    const float* bmd = (const float*)d_in[16];
    const float* bcd = (const float*)d_in[18];
    const float* lnw = (const float*)d_in[19];
    const float* lnb = (const float*)d_in[20];
    float* out = (float*)d_out;

    char* wsb = (char*)d_ws;
    short* wbf = (short*)wsb;                       // 8*65536*2 = 1 MiB
    short* mq  = (short*)(wsb + (1 << 20));
    short* mk  = mq  + TSZ;
    short* sq  = mk  + TSZ;
    short* sk  = sq  + TSZ;
    short* mvT = sk  + TSZ;
    short* cvT = mvT + TSZ;
    float* psums = (float*)(cvT + TSZ);             // 4 * 131072 f32 = 2 MiB
    short* mctx = (short*)(psums + 4 * (size_t)PSN);
    short* cctx = mctx + TSZ;

    float* probs = out + PROBS_OFF;

    hipLaunchKernelGGL(k_w2bf, dim3(512), dim3(256), 0, stream, src, wbf);
    hipLaunchKernelGGL(k_proj, dim3(512, 4, 6), dim3(256), 0, stream,
                       x_mean, x_cov, wbf, bp, mq, mk, sq, sk, mvT, cvT, psums);
    hipLaunchKernelGGL(k_attn, dim3(BH_ * 16), dim3(256), 0, stream,
                       mq, mk, sq, sk, mvT, cvT, psums, mask, probs, mctx, cctx);
    hipLaunchKernelGGL(k_final, dim3(BS_ / 32, 2), dim3(256), 0, stream,
                       mctx, cctx, wbf, bmd, bcd, x_mean, x_cov, lnw, lnb, out);
}

// Round 4
// 412.638 us; speedup vs baseline: 1.1889x; 1.0886x over previous
//
#include <hip/hip_runtime.h>
#include <math.h>

// ---------------- problem constants ----------------
#define B_    64
#define S_    512
#define HID_  256
#define NH_   4
#define DH_   64
#define BH_   (B_*NH_)            // 256 head-batches
#define BS_   (B_*S_)             // 32768 rows
#define TSZ   (BH_*S_*DH_)        // 8,388,608 bf16 elems per projected tensor
#define PSN   (BH_*S_)            // 131072 rows (per-head row-norm arrays)
#define MEANH_ELEMS (BS_*HID_)    // 8,388,608
#define PROBS_OFF   (2*MEANH_ELEMS)

typedef __attribute__((ext_vector_type(8))) short s16x8;
typedef __attribute__((ext_vector_type(4))) short s16x4;
typedef __attribute__((ext_vector_type(4))) float f32x4;

#define MFMA16(acc, a, b) (acc) = __builtin_amdgcn_mfma_f32_16x16x32_bf16((a), (b), (acc), 0, 0, 0)

static __device__ __forceinline__ short f2bf(float f) {
    union { float f; unsigned u; } a; a.f = f;
    unsigned r = a.u + 0x7fffu + ((a.u >> 16) & 1u);   // RNE
    return (short)(r >> 16);
}
static __device__ __forceinline__ float b2f(short s) {
    union { unsigned u; float f; } a; a.u = ((unsigned)(unsigned short)s) << 16;
    return a.f;
}
static __device__ __forceinline__ unsigned cvt_pk_bf16(float a, float b) {
    unsigned r;
    asm("v_cvt_pk_bf16_f32 %0, %1, %2" : "=v"(r) : "v"(a), "v"(b));
    return r;   // lo = bf16(a), hi = bf16(b), RNE
}
static __device__ __forceinline__ void unpk2(int u, float& lo, float& hi) {
    union { unsigned u; float f; } a, b;
    a.u = ((unsigned)u) << 16;
    b.u = ((unsigned)u) & 0xffff0000u;
    lo = a.f; hi = b.f;
}

// ---------------- kernel 1: weights f32 -> bf16 ----------------
struct WSrc { const float* w[8]; };

__global__ __launch_bounds__(256) void k_w2bf(WSrc src, short* wbf) {
    int t  = blockIdx.x * 256 + threadIdx.x;   // 131072 threads, 4 elems each
    int e4 = t * 4;
    int mi = e4 >> 16; int off = e4 & 65535;
    f32x4 v = *(const f32x4*)(src.w[mi] + off);
    s16x4 o;
    o[0] = f2bf(v[0]); o[1] = f2bf(v[1]); o[2] = f2bf(v[2]); o[3] = f2bf(v[3]);
    *(s16x4*)(wbf + mi * 65536 + off) = o;
}

// ---------------- kernel 2: QKV projections (+ fused row-norms) ----------------
// bz: 0 mq, 1 mk, 2 mv(->mvT), 3 sq=sqrt(elu+1), 4 sk, 5 cv=elu+1(->cvT)
// psums: [4][PSN] f32 row-norms of the STORED bf16 values:
//   0:||mq||^2  1:||mk||^2  2:||sq||^2  3:||sk||^2
struct BiasP { const float* b[6]; };

__global__ __launch_bounds__(256) void k_proj(const float* Xmean, const float* Xcov,
                                              const short* wbf, BiasP bp,
                                              short* mq, short* mk, short* sq, short* sk,
                                              short* mvT, short* cvT, float* psums) {
    const int bz = blockIdx.z;
    const float* X = (bz < 3) ? Xmean : Xcov;
    const short* W = wbf + bz * 65536;
    const float* bias = bp.b[bz];
    const int m0 = blockIdx.x * 64, n0 = blockIdx.y * 64;
    const int tid = threadIdx.x, wv = tid >> 6, l = tid & 63;

    __shared__ __align__(16) short x_l[64][40];   // 32 used + pad
    __shared__ __align__(16) short w_l[64][40];
    __shared__ __align__(16) short t_l[64][65];   // transpose staging (odd stride)

    f32x4 zero4 = {0.f, 0.f, 0.f, 0.f};
    f32x4 acc[4] = {zero4, zero4, zero4, zero4};

    for (int kk = 0; kk < 8; kk++) {
        const int k0 = kk * 32;
        #pragma unroll
        for (int i = 0; i < 2; i++) {               // X tile: 64x32 f32 -> bf16
            int g = tid + i * 256; int mr = g >> 3, ci = g & 7;
            f32x4 xv = *(const f32x4*)(X + (size_t)(m0 + mr) * HID_ + k0 + ci * 4);
            s16x4 xs; xs[0] = f2bf(xv[0]); xs[1] = f2bf(xv[1]); xs[2] = f2bf(xv[2]); xs[3] = f2bf(xv[3]);
            *(s16x4*)&x_l[mr][ci * 4] = xs;
        }
        {                                            // W tile: 64x32 bf16
            int o = tid >> 2, ci = tid & 3;
            *(s16x8*)&w_l[o][ci * 8] = *(const s16x8*)(W + (n0 + o) * HID_ + k0 + ci * 8);
        }
        __syncthreads();
        s16x8 a = *(const s16x8*)&x_l[wv * 16 + (l & 15)][8 * (l >> 4)];
        #pragma unroll
        for (int nt = 0; nt < 4; nt++) {
            s16x8 b = *(const s16x8*)&w_l[nt * 16 + (l & 15)][8 * (l >> 4)];
            MFMA16(acc[nt], a, b);
        }
        __syncthreads();
    }

    const bool tr = (bz == 2 || bz == 5);
    const int bb = m0 >> 9;          // batch
    const int s0 = m0 & 511;         // seq base
    const int h  = blockIdx.y;       // head (BN=64 == DH)
    short* dstd = (bz == 0) ? mq : (bz == 1) ? mk : (bz == 3) ? sq : sk;

    float ps[4] = {0.f, 0.f, 0.f, 0.f};  // per-r row-norm partials (of stored bf16)

    #pragma unroll
    for (int nt = 0; nt < 4; nt++) {
        #pragma unroll
        for (int r = 0; r < 4; r++) {
            int ml = wv * 16 + 4 * (l >> 4) + r;
            int ol = nt * 16 + (l & 15);
            float val = acc[nt][r] + bias[n0 + ol];
            if (bz == 3 || bz == 4) {
                float e1 = (val > 0.f) ? val + 1.f : __expf(val);
                val = sqrtf(fmaxf(e1, 1e-24f));
            } else if (bz == 5) {
                val = (val > 0.f) ? val + 1.f : __expf(val);
            }
            short bfv = f2bf(val);
            if (bz == 0 || bz == 1 || bz == 3 || bz == 4) {
                float qv = b2f(bfv);          // norm of the bf16-rounded value
                ps[r] += qv * qv;
            }
            if (tr) t_l[ml][ol] = bfv;
            else    dstd[(((size_t)(bb * NH_ + h) * S_ + (s0 + ml)) * DH_) + ol] = bfv;
        }
    }
    if (bz != 2 && bz != 5) {
        const int aidx = (bz == 0) ? 0 : (bz == 1) ? 1 : (bz == 3) ? 2 : 3;
        float* PS = psums + (size_t)aidx * PSN;
        #pragma unroll
        for (int r = 0; r < 4; r++) {
            float s = ps[r];
            s += __shfl_xor(s, 1); s += __shfl_xor(s, 2);
            s += __shfl_xor(s, 4); s += __shfl_xor(s, 8);
            if ((l & 15) == 0) {
                int ml = wv * 16 + 4 * (l >> 4) + r;
                PS[(size_t)(bb * NH_ + h) * S_ + (s0 + ml)] = s;
            }
        }
    }
    if (tr) {
        __syncthreads();
        short* dst = (bz == 2) ? mvT : cvT;
        #pragma unroll
        for (int i = 0; i < 2; i++) {
            int g = tid + i * 256; int orow = g >> 3, ci = g & 7;
            s16x8 v;
            #pragma unroll
            for (int j = 0; j < 8; j++) v[j] = t_l[ci * 8 + j][orow];
            *(s16x8*)(dst + ((size_t)(bb * NH_ + h) * DH_ + orow) * S_ + s0 + ci * 8) = v;
        }
    }
}

// ---------------- kernel 3: fused Wasserstein attention (v5) ----------------
// Round-0 skeleton: double-buffered kbuf QK (1 barrier/tile, write-other-
// buffer), P staged once to swizzled pT, coalesced probs epilogue from pT.
// New PV: each wave reads its own A-frag from pT (A/B frag lane layouts are
// identical), squares each P element ONCE, kq-split + red cross-wave
// reduction (v4-verified). smem lifetimes: kbuf -> pT -> red+obuf, all
// barrier-separated. LDS 37120B -> 4 blocks/CU.
__global__ __launch_bounds__(256, 4) void k_attn(const short* mq, const short* mk,
                                                 const short* sq, const short* sk,
                                                 const short* mvT, const short* cvT,
                                                 const float* psums,
                                                 const float* mask, float* probs,
                                                 short* mctx, short* cctx) {
    const int vb = (blockIdx.x & 7) * 512 + (blockIdx.x >> 3);   // XCD grouping
    const int bh = vb >> 4, qb = vb & 15;
    const int b = bh >> 2, h = bh & 3;
    const int q0 = qb * 32;
    const int tid = threadIdx.x, w = tid >> 6, l = tid & 63;
    const int mt = w & 1, kq = w >> 1;        // q-tile (16 rows), k-half (256 k)
    const int lg = l >> 4, lr = l & 15;

    // smem: kbuf[2][2][64][72] (36864B, QK) / pT[32][512] swizzled (32768B)
    //       / red[2][32][65]+obuf[2][32][72] (25856B, epilogue)
    __shared__ __align__(16) char smem[36864];
    __shared__ float rsum_l[32][2];
    short* s16p = (short*)smem;
#define KB(buf, t, row, col) (s16p + (((buf) * 2 + (t)) * 64 + (row)) * 72 + (col))
#define SWZ(row) ((((row) & 7) << 4) ^ (((row) & 8) << 3))

    // --- Q fragments + row norm (precomputed from bf16-rounded values) ---
    const int qrow = q0 + mt * 16 + lr;
    const size_t qoff = (size_t)bh * S_ + qrow;
    const short* mqR = mq + qoff * DH_;
    const short* sqR = sq + qoff * DH_;
    s16x8 qm0 = *(const s16x8*)(mqR + 8 * lg);
    s16x8 qm1 = *(const s16x8*)(mqR + 32 + 8 * lg);
    s16x8 qv0 = *(const s16x8*)(sqR + 8 * lg);
    s16x8 qv1 = *(const s16x8*)(sqR + 32 + 8 * lg);
    const float qsv = psums[qoff] + psums[2 * (size_t)PSN + qoff];

    const short* mkB = mk + (size_t)bh * (S_ * DH_);
    const short* skB = sk + (size_t)bh * (S_ * DH_);
    const float* ksMB = psums + 1 * (size_t)PSN + bh * S_;
    const float* ksSB = psums + 3 * (size_t)PSN + bh * S_;
    const float* maskR = mask + (size_t)b * (S_ * S_) + (size_t)qrow * S_;

    // K staging (issue-early / write-late, double-buffered, 1 barrier per tile)
    const int srow = tid >> 3, sci = (tid & 7) * 8;
    s16x8 Rm[2], Rs[2];
    auto ldK = [&](int kt) {
        #pragma unroll
        for (int i = 0; i < 2; i++) {
            int row = kt * 64 + srow + i * 32;
            Rm[i] = *(const s16x8*)(mkB + row * 64 + sci);
            Rs[i] = *(const s16x8*)(skB + row * 64 + sci);
        }
    };
    auto wrK = [&](int buf) {
        #pragma unroll
        for (int i = 0; i < 2; i++) {
            *(s16x8*)KB(buf, 0, srow + i * 32, sci) = Rm[i];
            *(s16x8*)KB(buf, 1, srow + i * 32, sci) = Rs[i];
        }
    };

    ldK(0); wrK(0); ldK(1);
    __syncthreads();

    // ---- QK phase (Round-0 exact) ----
    s16x4 pb[8][2];
    float rs = 0.f;
    #pragma unroll
    for (int kt = 0; kt < 8; kt++) {
        const int cb = kt & 1;
        #pragma unroll
        for (int nn = 0; nn < 2; nn++) {
            const int krl = kq * 32 + nn * 16 + lr;
            s16x8 am0 = *(const s16x8*)KB(cb, 0, krl, 8 * lg);
            s16x8 am1 = *(const s16x8*)KB(cb, 0, krl, 32 + 8 * lg);
            s16x8 as0 = *(const s16x8*)KB(cb, 1, krl, 8 * lg);
            s16x8 as1 = *(const s16x8*)KB(cb, 1, krl, 32 + 8 * lg);
            const int kbase = kt * 64 + kq * 32 + nn * 16 + 4 * lg;
            f32x4 kvM = *(const f32x4*)(ksMB + kbase);
            f32x4 kvS = *(const f32x4*)(ksSB + kbase);
            f32x4 mkv = *(const f32x4*)(maskR + kbase);
            f32x4 acc = {0.f, 0.f, 0.f, 0.f};
            MFMA16(acc, am0, qm0); MFMA16(acc, am1, qm1);
            MFMA16(acc, as0, qv0); MFMA16(acc, as1, qv1);
            float p[4];
            #pragma unroll
            for (int r = 0; r < 4; r++) {
                float dist = qsv + kvM[r] + kvS[r] - 2.f * acc[r];
                float t = __expf(-dist) * 0.125f;
                float pp = __expf(t + mkv[r]);      // scores tiny: no max-subtract
                rs += pp; p[r] = pp;
            }
            union { unsigned u[2]; s16x4 v; } pk;
            pk.u[0] = cvt_pk_bf16(p[0], p[1]);
            pk.u[1] = cvt_pk_bf16(p[2], p[3]);
            pb[kt][nn] = pk.v;
        }
        if (kt < 7) {
            wrK(cb ^ 1);                  // writes other buffer: no conflict with readers
            if (kt < 6) ldK(kt + 2);      // loads stay in flight across the barrier
        }
        __syncthreads();                  // kt=7: doubles as kbuf-dead fence
    }

    // ---- row sums + P -> pT (swizzled; overlays kbuf, safe after last barrier) ----
    rs += __shfl_xor(rs, 16); rs += __shfl_xor(rs, 32);
    if (l < 16) rsum_l[mt * 16 + l][kq] = rs;
    {
        const int wrow = mt * 16 + lr;
        const int sw = SWZ(wrow);
        #pragma unroll
        for (int kt = 0; kt < 8; kt++)
            #pragma unroll
            for (int nn = 0; nn < 2; nn++) {
                int colb = (kt * 64 + kq * 32 + nn * 16 + 4 * lg) * 2;
                *(s16x4*)(smem + wrow * 1024 + (colb ^ sw)) = pb[kt][nn];
            }
    }
    __syncthreads();

    // ---- probs output (coalesced 256B segments per 8-lane group, Round-0 exact) ----
    {
        const int prow = tid >> 3, pc = tid & 7;
        const int sw = SWZ(prow);
        const float rvp = 1.f / (rsum_l[prow][0] + rsum_l[prow][1]);
        float* probsB = probs + (size_t)bh * (S_ * S_) + (size_t)(q0 + prow) * S_;
        #pragma unroll
        for (int i = 0; i < 8; i++) {
            int k0 = pc * 8 + i * 64;
            s16x8 pv = *(const s16x8*)(smem + prow * 1024 + ((k0 * 2) ^ sw));
            f32x4 o0, o1;
            #pragma unroll
            for (int j = 0; j < 4; j++) { o0[j] = b2f(pv[j]) * rvp; o1[j] = b2f(pv[4 + j]) * rvp; }
            *(f32x4*)(probsB + k0) = o0;
            *(f32x4*)(probsB + k0 + 4) = o1;
        }
    }

    // ---- PV: wave (mt,kq) reads its OWN A-frag from pT once per kt; squares once ----
    // A-frag lane (lg,lr): P[q = mt*16+lr][k = kt*64 + kq*32 + 8*lg + j], j=0..7.
    const short* mvB = mvT + (size_t)bh * (DH_ * S_) + kq * 32 + 8 * lg;
    const short* cvB = cvT + (size_t)bh * (DH_ * S_) + kq * 32 + 8 * lg;
    const int arow = mt * 16 + lr;
    const int asw = SWZ(arow);

    f32x4 zero4 = {0.f, 0.f, 0.f, 0.f};
    f32x4 cm[4] = {zero4, zero4, zero4, zero4};  // ctx[q=mt*16+4lg+r][d=dt*16+lr]
    f32x4 cc[4] = {zero4, zero4, zero4, zero4};

    #pragma unroll
    for (int kt = 0; kt < 8; kt++) {
        // hoisted V^T loads (named regs)
        s16x8 VM0 = *(const s16x8*)(mvB + (size_t)(0 * 16 + lr) * S_ + kt * 64);
        s16x8 VM1 = *(const s16x8*)(mvB + (size_t)(1 * 16 + lr) * S_ + kt * 64);
        s16x8 VM2 = *(const s16x8*)(mvB + (size_t)(2 * 16 + lr) * S_ + kt * 64);
        s16x8 VM3 = *(const s16x8*)(mvB + (size_t)(3 * 16 + lr) * S_ + kt * 64);
        s16x8 VC0 = *(const s16x8*)(cvB + (size_t)(0 * 16 + lr) * S_ + kt * 64);
        s16x8 VC1 = *(const s16x8*)(cvB + (size_t)(1 * 16 + lr) * S_ + kt * 64);
        s16x8 VC2 = *(const s16x8*)(cvB + (size_t)(2 * 16 + lr) * S_ + kt * 64);
        s16x8 VC3 = *(const s16x8*)(cvB + (size_t)(3 * 16 + lr) * S_ + kt * 64);

        union { int i[4]; s16x8 v; } af, af2;
        af.v = *(const s16x8*)(smem + arow * 1024 + ((kt * 128 + kq * 64 + 16 * lg) ^ asw));
        float f0, f1, f2, f3, f4, f5, f6, f7;
        unpk2(af.i[0], f0, f1); unpk2(af.i[1], f2, f3);
        unpk2(af.i[2], f4, f5); unpk2(af.i[3], f6, f7);
        af2.i[0] = (int)cvt_pk_bf16(f0 * f0, f1 * f1);
        af2.i[1] = (int)cvt_pk_bf16(f2 * f2, f3 * f3);
        af2.i[2] = (int)cvt_pk_bf16(f4 * f4, f5 * f5);
        af2.i[3] = (int)cvt_pk_bf16(f6 * f6, f7 * f7);

        MFMA16(cm[0], af.v, VM0);  MFMA16(cm[1], af.v, VM1);
        MFMA16(cm[2], af.v, VM2);  MFMA16(cm[3], af.v, VM3);
        MFMA16(cc[0], af2.v, VC0); MFMA16(cc[1], af2.v, VC1);
        MFMA16(cc[2], af2.v, VC2); MFMA16(cc[3], af2.v, VC3);
    }

    __syncthreads();                             // pT dead (PV + probs reads done)

    // ---- ctx cross-wave (kq) reduction + epilogue (v4-verified, overlaid) ----
    float* red0 = (float*)smem;                  // [32][65] f32
    float* red1 = red0 + 32 * 65;                // [32][65] f32
    short* obufp = (short*)(smem + 16640);       // [2][32][72] shorts = 9216B
    if (kq == 0) {
        #pragma unroll
        for (int dt = 0; dt < 4; dt++)
            #pragma unroll
            for (int r = 0; r < 4; r++) {
                int row = mt * 16 + 4 * lg + r;
                red0[row * 65 + dt * 16 + lr] = cm[dt][r];
                red1[row * 65 + dt * 16 + lr] = cc[dt][r];
            }
    }
    __syncthreads();
    if (kq == 1) {
        #pragma unroll
        for (int r = 0; r < 4; r++) {
            const int row = mt * 16 + 4 * lg + r;
            const float rv = 1.f / (rsum_l[row][0] + rsum_l[row][1]);
            #pragma unroll
            for (int dt = 0; dt < 4; dt++) {
                float vm = (red0[row * 65 + dt * 16 + lr] + cm[dt][r]) * rv;
                float vc = (red1[row * 65 + dt * 16 + lr] + cc[dt][r]) * rv * rv;
                obufp[row * 72 + dt * 16 + lr] = f2bf(vm);
                obufp[(32 + row) * 72 + dt * 16 + lr] = f2bf(vc);
            }
        }
    }
    __syncthreads();
    {
        const int row = tid >> 3, pc = tid & 7;
        s16x8 vm = *(const s16x8*)(obufp + row * 72 + pc * 8);
        s16x8 vc = *(const s16x8*)(obufp + (32 + row) * 72 + pc * 8);
        size_t base = ((size_t)(b * S_ + q0 + row)) * HID_ + h * DH_ + pc * 8;
        *(s16x8*)(mctx + base) = vm;
        *(s16x8*)(cctx + base) = vc;
    }
#undef KB
#undef SWZ
}

// ---------------- kernel 4: output dense + residual + LayerNorm ----------------
__global__ __launch_bounds__(256) void k_final(const short* mctx, const short* cctx,
                                               const short* wbf,
                                               const float* bmd, const float* bcd,
                                               const float* Xmean, const float* Xcov,
                                               const float* lnw, const float* lnb,
                                               float* outbase) {
    const int which = blockIdx.y;
    const short* C = which ? cctx : mctx;
    const short* W = wbf + (6 + which) * 65536;
    const float* bias = which ? bcd : bmd;
    const float* X = which ? Xcov : Xmean;
    float* out = outbase + (size_t)which * MEANH_ELEMS;

    const int m0 = blockIdx.x * 32;
    const int tid = threadIdx.x, wv = tid >> 6, l = tid & 63;

    __shared__ __align__(16) short c_l[32][40];
    __shared__ __align__(16) short w_l[256][40];
    __shared__ float h_l[32][256];

    f32x4 zero4 = {0.f, 0.f, 0.f, 0.f};
    f32x4 acc[2][4];
    #pragma unroll
    for (int mtI = 0; mtI < 2; mtI++)
        #pragma unroll
        for (int nt = 0; nt < 4; nt++) acc[mtI][nt] = zero4;

    for (int kk = 0; kk < 8; kk++) {
        const int k0 = kk * 32;
        if (tid < 128) {
            int row = tid >> 2, ci = tid & 3;
            *(s16x8*)&c_l[row][ci * 8] = *(const s16x8*)(C + (size_t)(m0 + row) * HID_ + k0 + ci * 8);
        }
        #pragma unroll
        for (int i = 0; i < 4; i++) {
            int g = tid + i * 256; int o = g >> 2, ci = g & 3;
            *(s16x8*)&w_l[o][ci * 8] = *(const s16x8*)(W + o * HID_ + k0 + ci * 8);
        }
        __syncthreads();
        s16x8 a[2];
        #pragma unroll
        for (int mtI = 0; mtI < 2; mtI++)
            a[mtI] = *(const s16x8*)&c_l[mtI * 16 + (l & 15)][8 * (l >> 4)];
        #pragma unroll
        for (int nt = 0; nt < 4; nt++) {
            s16x8 bfr = *(const s16x8*)&w_l[wv * 64 + nt * 16 + (l & 15)][8 * (l >> 4)];
            MFMA16(acc[0][nt], a[0], bfr);
            MFMA16(acc[1][nt], a[1], bfr);
        }
        __syncthreads();
    }
    #pragma unroll
    for (int mtI = 0; mtI < 2; mtI++) {
        #pragma unroll
        for (int nt = 0; nt < 4; nt++) {
            #pragma unroll
            for (int r = 0; r < 4; r++) {
                int ml = mtI * 16 + 4 * (l >> 4) + r;
                int o = wv * 64 + nt * 16 + (l & 15);
                h_l[ml][o] = acc[mtI][nt][r] + bias[o] + X[(size_t)(m0 + ml) * HID_ + o];
            }
        }
    }
    __syncthreads();
    // LayerNorm: each wave owns 8 rows
    #pragma unroll
    for (int i = 0; i < 8; i++) {
        int row = wv * 8 + i;
        float s = 0.f;
        #pragma unroll
        for (int c = 0; c < 4; c++) s += h_l[row][l + c * 64];
        #pragma unroll
        for (int m = 1; m < 64; m <<= 1) s += __shfl_xor(s, m);
        float u = s * (1.f / 256.f);
        float s2 = 0.f;
        #pragma unroll
        for (int c = 0; c < 4; c++) { float d = h_l[row][l + c * 64] - u; s2 += d * d; }
        #pragma unroll
        for (int m = 1; m < 64; m <<= 1) s2 += __shfl_xor(s2, m);
        float rstd = rsqrtf(s2 * (1.f / 256.f) + 1e-12f);
        #pragma unroll
        for (int c = 0; c < 4; c++) {
            int o = l + c * 64;
            out[(size_t)(m0 + row) * HID_ + o] = lnw[o] * ((h_l[row][o] - u) * rstd) + lnb[o];
        }
    }
}

// ---------------- host ----------------
extern "C" void kernel_launch(void* const* d_in, const int* in_sizes, int n_in,
                              void* d_out, int out_size, void* d_ws, size_t ws_size,
                              hipStream_t stream) {
    const float* x_mean = (const float*)d_in[0];
    const float* x_cov  = (const float*)d_in[1];
    const float* mask   = (const float*)d_in[2];
    // weight order in wbf: Wmq Wmk Wmv Wcq Wck Wcv Wmd Wcd
    WSrc src;
    src.w[0] = (const float*)d_in[3];  src.w[1] = (const float*)d_in[5];
    src.w[2] = (const float*)d_in[7];  src.w[3] = (const float*)d_in[9];
    src.w[4] = (const float*)d_in[11]; src.w[5] = (const float*)d_in[13];
    src.w[6] = (const float*)d_in[15]; src.w[7] = (const float*)d_in[17];
    BiasP bp;
    bp.b[0] = (const float*)d_in[4];  bp.b[1] = (const float*)d_in[6];
    bp.b[2] = (const float*)d_in[8];  bp.b[3] = (const float*)d_in[10];
    bp.b[4] = (const float*)d_in[12]; bp.b[5] = (const float*)d_in[14];
    const float* bmd = (const float*)d_in[16];
    const float* bcd = (const float*)d_in[18];
    const float* lnw = (const float*)d_in[19];
    const float* lnb = (const float*)d_in[20];
    float* out = (float*)d_out;

    char* wsb = (char*)d_ws;
    short* wbf = (short*)wsb;                       // 8*65536*2 = 1 MiB
    short* mq  = (short*)(wsb + (1 << 20));
    short* mk  = mq  + TSZ;
    short* sq  = mk  + TSZ;
    short* sk  = sq  + TSZ;
    short* mvT = sk  + TSZ;
    short* cvT = mvT + TSZ;
    float* psums = (float*)(cvT + TSZ);             // 4 * 131072 f32 = 2 MiB
    short* mctx = (short*)(psums + 4 * (size_t)PSN);
    short* cctx = mctx + TSZ;

    float* probs = out + PROBS_OFF;

    hipLaunchKernelGGL(k_w2bf, dim3(512), dim3(256), 0, stream, src, wbf);
    hipLaunchKernelGGL(k_proj, dim3(512, 4, 6), dim3(256), 0, stream,
                       x_mean, x_cov, wbf, bp, mq, mk, sq, sk, mvT, cvT, psums);
    hipLaunchKernelGGL(k_attn, dim3(BH_ * 16), dim3(256), 0, stream,
                       mq, mk, sq, sk, mvT, cvT, psums, mask, probs, mctx, cctx);
    hipLaunchKernelGGL(k_final, dim3(BS_ / 32, 2), dim3(256), 0, stream,
                       mctx, cctx, wbf, bmd, bcd, x_mean, x_cov, lnw, lnb, out);
}

// Round 5
// 388.278 us; speedup vs baseline: 1.2635x; 1.0627x over previous
//
#include <hip/hip_runtime.h>
#include <math.h>

// ---------------- problem constants ----------------
#define B_    64
#define S_    512
#define HID_  256
#define NH_   4
#define DH_   64
#define BH_   (B_*NH_)            // 256 head-batches
#define BS_   (B_*S_)             // 32768 rows
#define TSZ   (BH_*S_*DH_)        // 8,388,608 bf16 elems per projected tensor
#define PSN   (BH_*S_)            // 131072 rows (per-head row-norm arrays)
#define MEANH_ELEMS (BS_*HID_)    // 8,388,608
#define PROBS_OFF   (2*MEANH_ELEMS)

typedef __attribute__((ext_vector_type(8))) short s16x8;
typedef __attribute__((ext_vector_type(4))) short s16x4;
typedef __attribute__((ext_vector_type(4))) float f32x4;

#define MFMA16(acc, a, b) (acc) = __builtin_amdgcn_mfma_f32_16x16x32_bf16((a), (b), (acc), 0, 0, 0)

static __device__ __forceinline__ short f2bf(float f) {
    union { float f; unsigned u; } a; a.f = f;
    unsigned r = a.u + 0x7fffu + ((a.u >> 16) & 1u);   // RNE
    return (short)(r >> 16);
}
static __device__ __forceinline__ float b2f(short s) {
    union { unsigned u; float f; } a; a.u = ((unsigned)(unsigned short)s) << 16;
    return a.f;
}
static __device__ __forceinline__ unsigned cvt_pk_bf16(float a, float b) {
    unsigned r;
    asm("v_cvt_pk_bf16_f32 %0, %1, %2" : "=v"(r) : "v"(a), "v"(b));
    return r;   // lo = bf16(a), hi = bf16(b), RNE
}
static __device__ __forceinline__ void unpk2(int u, float& lo, float& hi) {
    union { unsigned u; float f; } a, b;
    a.u = ((unsigned)u) << 16;
    b.u = ((unsigned)u) & 0xffff0000u;
    lo = a.f; hi = b.f;
}

// ---------------- kernel 1: weights f32 -> bf16 ----------------
struct WSrc { const float* w[8]; };

__global__ __launch_bounds__(256) void k_w2bf(WSrc src, short* wbf) {
    int t  = blockIdx.x * 256 + threadIdx.x;   // 131072 threads, 4 elems each
    int e4 = t * 4;
    int mi = e4 >> 16; int off = e4 & 65535;
    f32x4 v = *(const f32x4*)(src.w[mi] + off);
    s16x4 o;
    o[0] = f2bf(v[0]); o[1] = f2bf(v[1]); o[2] = f2bf(v[2]); o[3] = f2bf(v[3]);
    *(s16x4*)(wbf + mi * 65536 + off) = o;
}

// ---------------- kernel 2: QKV projections (+ fused row-norms) ----------------
// bz: 0 mq, 1 mk, 2 mv(->mvT), 3 sq=sqrt(elu+1), 4 sk, 5 cv=elu+1(->cvT)
// psums: [4][PSN] f32 row-norms of the STORED bf16 values:
//   0:||mq||^2  1:||mk||^2  2:||sq||^2  3:||sk||^2
struct BiasP { const float* b[6]; };

__global__ __launch_bounds__(256) void k_proj(const float* Xmean, const float* Xcov,
                                              const short* wbf, BiasP bp,
                                              short* mq, short* mk, short* sq, short* sk,
                                              short* mvT, short* cvT, float* psums) {
    const int bz = blockIdx.z;
    const float* X = (bz < 3) ? Xmean : Xcov;
    const short* W = wbf + bz * 65536;
    const float* bias = bp.b[bz];
    const int m0 = blockIdx.x * 64, n0 = blockIdx.y * 64;
    const int tid = threadIdx.x, wv = tid >> 6, l = tid & 63;

    __shared__ __align__(16) short x_l[64][40];   // 32 used + pad
    __shared__ __align__(16) short w_l[64][40];
    __shared__ __align__(16) short t_l[64][65];   // transpose staging (odd stride)

    f32x4 zero4 = {0.f, 0.f, 0.f, 0.f};
    f32x4 acc[4] = {zero4, zero4, zero4, zero4};

    for (int kk = 0; kk < 8; kk++) {
        const int k0 = kk * 32;
        #pragma unroll
        for (int i = 0; i < 2; i++) {               // X tile: 64x32 f32 -> bf16
            int g = tid + i * 256; int mr = g >> 3, ci = g & 7;
            f32x4 xv = *(const f32x4*)(X + (size_t)(m0 + mr) * HID_ + k0 + ci * 4);
            s16x4 xs; xs[0] = f2bf(xv[0]); xs[1] = f2bf(xv[1]); xs[2] = f2bf(xv[2]); xs[3] = f2bf(xv[3]);
            *(s16x4*)&x_l[mr][ci * 4] = xs;
        }
        {                                            // W tile: 64x32 bf16
            int o = tid >> 2, ci = tid & 3;
            *(s16x8*)&w_l[o][ci * 8] = *(const s16x8*)(W + (n0 + o) * HID_ + k0 + ci * 8);
        }
        __syncthreads();
        s16x8 a = *(const s16x8*)&x_l[wv * 16 + (l & 15)][8 * (l >> 4)];
        #pragma unroll
        for (int nt = 0; nt < 4; nt++) {
            s16x8 b = *(const s16x8*)&w_l[nt * 16 + (l & 15)][8 * (l >> 4)];
            MFMA16(acc[nt], a, b);
        }
        __syncthreads();
    }

    const bool tr = (bz == 2 || bz == 5);
    const int bb = m0 >> 9;          // batch
    const int s0 = m0 & 511;         // seq base
    const int h  = blockIdx.y;       // head (BN=64 == DH)
    short* dstd = (bz == 0) ? mq : (bz == 1) ? mk : (bz == 3) ? sq : sk;

    float ps[4] = {0.f, 0.f, 0.f, 0.f};  // per-r row-norm partials (of stored bf16)

    #pragma unroll
    for (int nt = 0; nt < 4; nt++) {
        #pragma unroll
        for (int r = 0; r < 4; r++) {
            int ml = wv * 16 + 4 * (l >> 4) + r;
            int ol = nt * 16 + (l & 15);
            float val = acc[nt][r] + bias[n0 + ol];
            if (bz == 3 || bz == 4) {
                float e1 = (val > 0.f) ? val + 1.f : __expf(val);
                val = sqrtf(fmaxf(e1, 1e-24f));
            } else if (bz == 5) {
                val = (val > 0.f) ? val + 1.f : __expf(val);
            }
            short bfv = f2bf(val);
            if (bz == 0 || bz == 1 || bz == 3 || bz == 4) {
                float qv = b2f(bfv);          // norm of the bf16-rounded value
                ps[r] += qv * qv;
            }
            if (tr) t_l[ml][ol] = bfv;
            else    dstd[(((size_t)(bb * NH_ + h) * S_ + (s0 + ml)) * DH_) + ol] = bfv;
        }
    }
    if (bz != 2 && bz != 5) {
        const int aidx = (bz == 0) ? 0 : (bz == 1) ? 1 : (bz == 3) ? 2 : 3;
        float* PS = psums + (size_t)aidx * PSN;
        #pragma unroll
        for (int r = 0; r < 4; r++) {
            float s = ps[r];
            s += __shfl_xor(s, 1); s += __shfl_xor(s, 2);
            s += __shfl_xor(s, 4); s += __shfl_xor(s, 8);
            if ((l & 15) == 0) {
                int ml = wv * 16 + 4 * (l >> 4) + r;
                PS[(size_t)(bb * NH_ + h) * S_ + (s0 + ml)] = s;
            }
        }
    }
    if (tr) {
        __syncthreads();
        short* dst = (bz == 2) ? mvT : cvT;
        #pragma unroll
        for (int i = 0; i < 2; i++) {
            int g = tid + i * 256; int orow = g >> 3, ci = g & 7;
            s16x8 v;
            #pragma unroll
            for (int j = 0; j < 8; j++) v[j] = t_l[ci * 8 + j][orow];
            *(s16x8*)(dst + ((size_t)(bb * NH_ + h) * DH_ + orow) * S_ + s0 + ci * 8) = v;
        }
    }
}

// ---------------- kernel 3: fused Wasserstein attention ----------------
// Round-0 verbatim schedule (measured 200us): swapped-operand QK (S^T = K.Q^T)
// with LDS-staged K double-buffer (1 barrier/tile), P staged once into
// swizzled pT[32][512], coalesced probs/ctx epilogues, explicit Vbuf[2]
// 1-kt-ahead V prefetch in PV. Only edits vs Round-0: ksum/qsv from fused
// psums (k_rowsum kernel deleted), and bp2 squaring packed via cvt_pk.
__global__ __launch_bounds__(256, 4) void k_attn(const short* mq, const short* mk,
                                                 const short* sq, const short* sk,
                                                 const short* mvT, const short* cvT,
                                                 const float* psums,
                                                 const float* mask, float* probs,
                                                 short* mctx, short* cctx) {
    const int vb = (blockIdx.x & 7) * 512 + (blockIdx.x >> 3);   // XCD grouping
    const int bh = vb >> 4, qb = vb & 15;
    const int b = bh >> 2, h = bh & 3;
    const int q0 = qb * 32;
    const int tid = threadIdx.x, w = tid >> 6, l = tid & 63;
    const int mt = w & 1, kq = w >> 1;        // q-tile (16 rows), k-half (256 k)
    const int lg = l >> 4, lr = l & 15;

    // union: kbuf[2][2][64][72] (36864B, QK phase) / pT[32][512] swizzled
    // (32768B, PV phase) / ctx_l (8192B, epilogue)
    __shared__ __align__(16) char smem[36864];
    __shared__ float rsum_l[32][2];
    short* s16p = (short*)smem;

#define KB(buf, t, row, col) (s16p + (((buf) * 2 + (t)) * 64 + (row)) * 72 + (col))
#define SWZ(row) ((((row) & 7) << 4) ^ (((row) & 8) << 3))

    const short* mkB = mk + (size_t)bh * (S_ * DH_);
    const short* skB = sk + (size_t)bh * (S_ * DH_);
    const float* ksMB = psums + 1 * (size_t)PSN + bh * S_;
    const float* ksSB = psums + 3 * (size_t)PSN + bh * S_;
    const float* maskR = mask + (size_t)b * (S_ * S_) + (size_t)(q0 + mt * 16 + lr) * S_;

    // Q B-frags (held in regs all of QK); per-lane q = q0 + mt*16 + lr
    const size_t qoff = (size_t)bh * S_ + (q0 + mt * 16 + lr);
    const short* mqR = mq + qoff * DH_;
    const short* sqR = sq + qoff * DH_;
    s16x8 qm0 = *(const s16x8*)(mqR + 8 * lg);
    s16x8 qm1 = *(const s16x8*)(mqR + 32 + 8 * lg);
    s16x8 qv0 = *(const s16x8*)(sqR + 8 * lg);
    s16x8 qv1 = *(const s16x8*)(sqR + 32 + 8 * lg);
    const float qsv = psums[qoff] + psums[2 * (size_t)PSN + qoff];

    // K staging (issue-early / write-late, double-buffered, 1 barrier per tile)
    const int srow = tid >> 3, sci = (tid & 7) * 8;
    s16x8 Rm[2], Rs[2];
    auto ldK = [&](int kt) {
        #pragma unroll
        for (int i = 0; i < 2; i++) {
            int row = kt * 64 + srow + i * 32;
            Rm[i] = *(const s16x8*)(mkB + row * 64 + sci);
            Rs[i] = *(const s16x8*)(skB + row * 64 + sci);
        }
    };
    auto wrK = [&](int buf) {
        #pragma unroll
        for (int i = 0; i < 2; i++) {
            *(s16x8*)KB(buf, 0, srow + i * 32, sci) = Rm[i];
            *(s16x8*)KB(buf, 1, srow + i * 32, sci) = Rs[i];
        }
    };

    ldK(0); wrK(0); ldK(1);
    __syncthreads();

    // ---- QK phase ----
    s16x4 pb[8][2];
    float rs = 0.f;
    #pragma unroll
    for (int kt = 0; kt < 8; kt++) {
        const int cb = kt & 1;
        #pragma unroll
        for (int nn = 0; nn < 2; nn++) {
            const int krl = kq * 32 + nn * 16 + lr;
            s16x8 am0 = *(const s16x8*)KB(cb, 0, krl, 8 * lg);
            s16x8 am1 = *(const s16x8*)KB(cb, 0, krl, 32 + 8 * lg);
            s16x8 as0 = *(const s16x8*)KB(cb, 1, krl, 8 * lg);
            s16x8 as1 = *(const s16x8*)KB(cb, 1, krl, 32 + 8 * lg);
            const int kbase = kt * 64 + kq * 32 + nn * 16 + 4 * lg;
            f32x4 kvM = *(const f32x4*)(ksMB + kbase);
            f32x4 kvS = *(const f32x4*)(ksSB + kbase);
            f32x4 mkv = *(const f32x4*)(maskR + kbase);
            f32x4 acc = {0.f, 0.f, 0.f, 0.f};
            MFMA16(acc, am0, qm0); MFMA16(acc, am1, qm1);
            MFMA16(acc, as0, qv0); MFMA16(acc, as1, qv1);
            s16x4 pv;
            #pragma unroll
            for (int r = 0; r < 4; r++) {
                float dist = qsv + kvM[r] + kvS[r] - 2.f * acc[r];
                float t = __expf(-dist) * 0.125f;
                float p = __expf(t + mkv[r]);        // scores tiny: no max-subtract
                rs += p;
                pv[r] = f2bf(p);
            }
            pb[kt][nn] = pv;
        }
        if (kt < 7) {
            wrK(cb ^ 1);                  // writes other buffer: no conflict with readers
            if (kt < 6) ldK(kt + 2);      // loads stay in flight across the barrier
        }
        __syncthreads();
    }

    // row sums (k is the register dim: reduce lg quarters) and P -> pT
    rs += __shfl_xor(rs, 16); rs += __shfl_xor(rs, 32);
    if (l < 16) rsum_l[mt * 16 + l][kq] = rs;
    {
        const int wrow = mt * 16 + lr;
        const int sw = SWZ(wrow);
        #pragma unroll
        for (int kt = 0; kt < 8; kt++)
            #pragma unroll
            for (int nn = 0; nn < 2; nn++) {
                int colb = (kt * 64 + kq * 32 + nn * 16 + 4 * lg) * 2;
                *(s16x4*)(smem + wrow * 1024 + (colb ^ sw)) = pb[kt][nn];
            }
    }
    // PV V prefetch (global), issued before the barrier
    const short* mvR = mvT + (size_t)bh * (DH_ * S_) + (size_t)(w * 16 + lr) * S_;
    const short* cvR = cvT + (size_t)bh * (DH_ * S_) + (size_t)(w * 16 + lr) * S_;
    s16x8 Vbuf[2][4];
    auto LDV = [&](int kt, s16x8* V) {
        V[0] = *(const s16x8*)(mvR + kt * 64 + 8 * lg);
        V[1] = *(const s16x8*)(mvR + kt * 64 + 32 + 8 * lg);
        V[2] = *(const s16x8*)(cvR + kt * 64 + 8 * lg);
        V[3] = *(const s16x8*)(cvR + kt * 64 + 32 + 8 * lg);
    };
    LDV(0, Vbuf[0]);
    __syncthreads();

    // ---- probs output (coalesced 256B segments per 8-lane group) ----
    {
        const int prow = tid >> 3, pc = tid & 7;
        const int sw = SWZ(prow);
        const float rvp = 1.f / (rsum_l[prow][0] + rsum_l[prow][1]);
        float* probsB = probs + (size_t)bh * (S_ * S_) + (size_t)(q0 + prow) * S_;
        #pragma unroll
        for (int i = 0; i < 8; i++) {
            int k0 = pc * 8 + i * 64;
            s16x8 pv = *(const s16x8*)(smem + prow * 1024 + ((k0 * 2) ^ sw));
            f32x4 o0, o1;
            #pragma unroll
            for (int j = 0; j < 4; j++) { o0[j] = b2f(pv[j]) * rvp; o1[j] = b2f(pv[4 + j]) * rvp; }
            *(f32x4*)(probsB + k0) = o0;
            *(f32x4*)(probsB + k0 + 4) = o1;
        }
    }

    // ---- PV: ctx^T[d][q] = mfma(A=V^T, B=P^T); P^2 via packed cvt ----
    float rvq[2];
    #pragma unroll
    for (int qt = 0; qt < 2; qt++)
        rvq[qt] = 1.f / (rsum_l[qt * 16 + lr][0] + rsum_l[qt * 16 + lr][1]);

    f32x4 zero4 = {0.f, 0.f, 0.f, 0.f};
    f32x4 om[2] = {zero4, zero4};
    f32x4 oc[2] = {zero4, zero4};
    #pragma unroll
    for (int kt = 0; kt < 8; kt++) {
        const int cur = kt & 1;
        if (kt < 7) LDV(kt + 1, Vbuf[cur ^ 1]);
        #pragma unroll
        for (int qt = 0; qt < 2; qt++) {
            const int brow = qt * 16 + lr;
            const int sw = SWZ(brow);
            #pragma unroll
            for (int koff = 0; koff < 2; koff++) {
                int byteoff = kt * 128 + koff * 64 + 16 * lg;
                union { int i[4]; s16x8 v; } bp, bp2;
                bp.v = *(const s16x8*)(smem + brow * 1024 + (byteoff ^ sw));
                float f0, f1, f2, f3, f4, f5, f6, f7;
                unpk2(bp.i[0], f0, f1); unpk2(bp.i[1], f2, f3);
                unpk2(bp.i[2], f4, f5); unpk2(bp.i[3], f6, f7);
                bp2.i[0] = (int)cvt_pk_bf16(f0 * f0, f1 * f1);
                bp2.i[1] = (int)cvt_pk_bf16(f2 * f2, f3 * f3);
                bp2.i[2] = (int)cvt_pk_bf16(f4 * f4, f5 * f5);
                bp2.i[3] = (int)cvt_pk_bf16(f6 * f6, f7 * f7);
                MFMA16(om[qt], Vbuf[cur][koff], bp.v);
                MFMA16(oc[qt], Vbuf[cur][2 + koff], bp2.v);
            }
        }
    }

    // ---- ctx epilogue: stage through LDS for 128B-coalesced stores ----
    __syncthreads();                     // pT dead
    char* cm = smem;                     // [32][64] bf16, 128B rows, swizzled
    char* cc = smem + 4096;
    #pragma unroll
    for (int qt = 0; qt < 2; qt++) {
        const int row = qt * 16 + lr;
        const int sw = SWZ(row);
        const float rv = rvq[qt];
        s16x4 vm, vc;
        #pragma unroll
        for (int r = 0; r < 4; r++) {
            vm[r] = f2bf(om[qt][r] * rv);
            vc[r] = f2bf(oc[qt][r] * rv * rv);
        }
        int colb = (w * 16 + 4 * lg) * 2;
        *(s16x4*)(cm + row * 128 + (colb ^ sw)) = vm;
        *(s16x4*)(cc + row * 128 + (colb ^ sw)) = vc;
    }
    __syncthreads();
    {
        const int row = tid >> 3, pc = tid & 7;
        const int sw = SWZ(row);
        s16x8 vm = *(const s16x8*)(cm + row * 128 + ((pc * 16) ^ sw));
        s16x8 vc = *(const s16x8*)(cc + row * 128 + ((pc * 16) ^ sw));
        size_t base = ((size_t)(b * S_ + q0 + row)) * HID_ + h * DH_ + pc * 8;
        *(s16x8*)(mctx + base) = vm;
        *(s16x8*)(cctx + base) = vc;
    }
#undef KB
#undef SWZ
}

// ---------------- kernel 4: output dense + residual + LayerNorm ----------------
__global__ __launch_bounds__(256) void k_final(const short* mctx, const short* cctx,
                                               const short* wbf,
                                               const float* bmd, const float* bcd,
                                               const float* Xmean, const float* Xcov,
                                               const float* lnw, const float* lnb,
                                               float* outbase) {
    const int which = blockIdx.y;
    const short* C = which ? cctx : mctx;
    const short* W = wbf + (6 + which) * 65536;
    const float* bias = which ? bcd : bmd;
    const float* X = which ? Xcov : Xmean;
    float* out = outbase + (size_t)which * MEANH_ELEMS;

    const int m0 = blockIdx.x * 32;
    const int tid = threadIdx.x, wv = tid >> 6, l = tid & 63;

    __shared__ __align__(16) short c_l[32][40];
    __shared__ __align__(16) short w_l[256][40];
    __shared__ float h_l[32][256];

    f32x4 zero4 = {0.f, 0.f, 0.f, 0.f};
    f32x4 acc[2][4];
    #pragma unroll
    for (int mtI = 0; mtI < 2; mtI++)
        #pragma unroll
        for (int nt = 0; nt < 4; nt++) acc[mtI][nt] = zero4;

    for (int kk = 0; kk < 8; kk++) {
        const int k0 = kk * 32;
        if (tid < 128) {
            int row = tid >> 2, ci = tid & 3;
            *(s16x8*)&c_l[row][ci * 8] = *(const s16x8*)(C + (size_t)(m0 + row) * HID_ + k0 + ci * 8);
        }
        #pragma unroll
        for (int i = 0; i < 4; i++) {
            int g = tid + i * 256; int o = g >> 2, ci = g & 3;
            *(s16x8*)&w_l[o][ci * 8] = *(const s16x8*)(W + o * HID_ + k0 + ci * 8);
        }
        __syncthreads();
        s16x8 a[2];
        #pragma unroll
        for (int mtI = 0; mtI < 2; mtI++)
            a[mtI] = *(const s16x8*)&c_l[mtI * 16 + (l & 15)][8 * (l >> 4)];
        #pragma unroll
        for (int nt = 0; nt < 4; nt++) {
            s16x8 bfr = *(const s16x8*)&w_l[wv * 64 + nt * 16 + (l & 15)][8 * (l >> 4)];
            MFMA16(acc[0][nt], a[0], bfr);
            MFMA16(acc[1][nt], a[1], bfr);
        }
        __syncthreads();
    }
    #pragma unroll
    for (int mtI = 0; mtI < 2; mtI++) {
        #pragma unroll
        for (int nt = 0; nt < 4; nt++) {
            #pragma unroll
            for (int r = 0; r < 4; r++) {
                int ml = mtI * 16 + 4 * (l >> 4) + r;
                int o = wv * 64 + nt * 16 + (l & 15);
                h_l[ml][o] = acc[mtI][nt][r] + bias[o] + X[(size_t)(m0 + ml) * HID_ + o];
            }
        }
    }
    __syncthreads();
    // LayerNorm: each wave owns 8 rows
    #pragma unroll
    for (int i = 0; i < 8; i++) {
        int row = wv * 8 + i;
        float s = 0.f;
        #pragma unroll
        for (int c = 0; c < 4; c++) s += h_l[row][l + c * 64];
        #pragma unroll
        for (int m = 1; m < 64; m <<= 1) s += __shfl_xor(s, m);
        float u = s * (1.f / 256.f);
        float s2 = 0.f;
        #pragma unroll
        for (int c = 0; c < 4; c++) { float d = h_l[row][l + c * 64] - u; s2 += d * d; }
        #pragma unroll
        for (int m = 1; m < 64; m <<= 1) s2 += __shfl_xor(s2, m);
        float rstd = rsqrtf(s2 * (1.f / 256.f) + 1e-12f);
        #pragma unroll
        for (int c = 0; c < 4; c++) {
            int o = l + c * 64;
            out[(size_t)(m0 + row) * HID_ + o] = lnw[o] * ((h_l[row][o] - u) * rstd) + lnb[o];
        }
    }
}

// ---------------- host ----------------
extern "C" void kernel_launch(void* const* d_in, const int* in_sizes, int n_in,
                              void* d_out, int out_size, void* d_ws, size_t ws_size,
                              hipStream_t stream) {
    const float* x_mean = (const float*)d_in[0];
    const float* x_cov  = (const float*)d_in[1];
    const float* mask   = (const float*)d_in[2];
    // weight order in wbf: Wmq Wmk Wmv Wcq Wck Wcv Wmd Wcd
    WSrc src;
    src.w[0] = (const float*)d_in[3];  src.w[1] = (const float*)d_in[5];
    src.w[2] = (const float*)d_in[7];  src.w[3] = (const float*)d_in[9];
    src.w[4] = (const float*)d_in[11]; src.w[5] = (const float*)d_in[13];
    src.w[6] = (const float*)d_in[15]; src.w[7] = (const float*)d_in[17];
    BiasP bp;
    bp.b[0] = (const float*)d_in[4];  bp.b[1] = (const float*)d_in[6];
    bp.b[2] = (const float*)d_in[8];  bp.b[3] = (const float*)d_in[10];
    bp.b[4] = (const float*)d_in[12]; bp.b[5] = (const float*)d_in[14];
    const float* bmd = (const float*)d_in[16];
    const float* bcd = (const float*)d_in[18];
    const float* lnw = (const float*)d_in[19];
    const float* lnb = (const float*)d_in[20];
    float* out = (float*)d_out;

    char* wsb = (char*)d_ws;
    short* wbf = (short*)wsb;                       // 8*65536*2 = 1 MiB
    short* mq  = (short*)(wsb + (1 << 20));
    short* mk  = mq  + TSZ;
    short* sq  = mk  + TSZ;
    short* sk  = sq  + TSZ;
    short* mvT = sk  + TSZ;
    short* cvT = mvT + TSZ;
    float* psums = (float*)(cvT + TSZ);             // 4 * 131072 f32 = 2 MiB
    short* mctx = (short*)(psums + 4 * (size_t)PSN);
    short* cctx = mctx + TSZ;

    float* probs = out + PROBS_OFF;

    hipLaunchKernelGGL(k_w2bf, dim3(512), dim3(256), 0, stream, src, wbf);
    hipLaunchKernelGGL(k_proj, dim3(512, 4, 6), dim3(256), 0, stream,
                       x_mean, x_cov, wbf, bp, mq, mk, sq, sk, mvT, cvT, psums);
    hipLaunchKernelGGL(k_attn, dim3(BH_ * 16), dim3(256), 0, stream,
                       mq, mk, sq, sk, mvT, cvT, psums, mask, probs, mctx, cctx);
    hipLaunchKernelGGL(k_final, dim3(BS_ / 32, 2), dim3(256), 0, stream,
                       mctx, cctx, wbf, bmd, bcd, x_mean, x_cov, lnw, lnb, out);
}